// Round 5
// baseline (661.465 us; speedup 1.0000x reference)
//
#include <hip/hip_runtime.h>
#include <hip/hip_bf16.h>
#include <cmath>

typedef __attribute__((ext_vector_type(8))) short bf16x8;
typedef __attribute__((ext_vector_type(4))) float f32x4;

__device__ __forceinline__ float bf2f(unsigned short u) {
    unsigned int x = ((unsigned int)u) << 16;
    return __builtin_bit_cast(float, x);
}
__device__ __forceinline__ unsigned short f2bf(float f) {
    unsigned int x = __builtin_bit_cast(unsigned int, f);
    unsigned int lsb = (x >> 16) & 1u;
    x += 0x7fffu + lsb;
    return (unsigned short)(x >> 16);
}
__device__ __forceinline__ float sigm(float z) {
    return 1.f / (1.f + __expf(-z));
}
__device__ __forceinline__ float rcpf(float x) { return __builtin_amdgcn_rcpf(x); }
__device__ __forceinline__ float sigm_f(float z) { return rcpf(1.f + __expf(-z)); }
__device__ __forceinline__ float tanh_f(float z) { return 1.f - 2.f * rcpf(1.f + __expf(2.f * z)); }

// Agent-coherent 16B load (bypasses non-coherent local caches -> IF$).
__device__ __forceinline__ bf16x8 ldg_sc(const unsigned short* p) {
    bf16x8 r;
    asm volatile("global_load_dwordx4 %0, %1, off sc1"
                 : "=v"(r) : "v"(p) : "memory");
    return r;
}

// h' = h+3 in (2,4): every bf16 high byte == 0x40. Returns 0 iff fragment valid.
__device__ __forceinline__ unsigned int frag_bad(bf16x8 v) {
    uint4 u = __builtin_bit_cast(uint4, v);
    return ((u.x & 0xFF00FF00u) ^ 0x40004000u) |
           ((u.y & 0xFF00FF00u) ^ 0x40004000u) |
           ((u.z & 0xFF00FF00u) ^ 0x40004000u) |
           ((u.w & 0xFF00FF00u) ^ 0x40004000u);
}

// in-quad 4x4 transpose (lane q holds M[q][:]; after: a[g] = M[g][q]).
__device__ __forceinline__ void tr4(float a[4], int q) {
    float u0 = (q & 1) ? a[0] : a[1];
    float u1 = (q & 1) ? a[2] : a[3];
    float v0 = __shfl_xor(u0, 1);
    float v1 = __shfl_xor(u1, 1);
    if (q & 1) { a[0] = v0; a[2] = v1; } else { a[1] = v0; a[3] = v1; }
    float w0 = (q & 2) ? a[0] : a[2];
    float w1 = (q & 2) ? a[1] : a[3];
    float s0 = __shfl_xor(w0, 2);
    float s1 = __shfl_xor(w1, 2);
    if (q & 2) { a[0] = s0; a[1] = s1; } else { a[2] = s0; a[3] = s1; }
}

// ---------------------------------------------------------------------------
// prep_M: M = WQ1^T @ WK1 in MFMA B-fragment order. Block 64 zeroes corr.
// ---------------------------------------------------------------------------
__global__ void __launch_bounds__(256) prep_M(const float* __restrict__ WQ1,
                                              const float* __restrict__ WK1,
                                              unsigned short* __restrict__ M_pk,
                                              float* __restrict__ corrA,
                                              float* __restrict__ corrB) {
    if (blockIdx.x == 64) {
        int tid = threadIdx.x;
        for (int i = tid; i < 1024; i += 256) corrA[i] = 0.f;
        for (int i = tid; i < 2048; i += 256) corrB[i] = 0.f;
        return;
    }
    __shared__ unsigned short As[256][32];
    __shared__ unsigned short Bs[256][32];
    int bx = blockIdx.x;
    int e0 = (bx >> 3) << 5;
    int f0 = (bx & 7) << 5;
    int tid = threadIdx.x;
    int col = tid & 31, rr = tid >> 5;
    for (int rep = 0; rep < 32; ++rep) {
        int d = rep * 8 + rr;
        As[d][col] = f2bf(WQ1[d * 256 + e0 + col]);
        Bs[d][col] = f2bf(WK1[d * 256 + f0 + col]);
    }
    __syncthreads();
    int el = tid & 31;
    int fl0 = tid >> 5;
    for (int i = 0; i < 4; ++i) {
        int fl = fl0 + 8 * i;
        float acc = 0.f;
        for (int d = 0; d < 256; ++d)
            acc += bf2f(As[d][el]) * bf2f(Bs[d][fl]);
        int e = e0 + el, f = f0 + fl;
        int kb = e >> 5, r = (e >> 3) & 3, j = e & 7;
        int nb = f >> 4;
        int lane = (r << 4) | (f & 15);
        M_pk[(((nb * 8 + kb) * 64) + lane) * 8 + j] = f2bf(acc);
    }
}

// ---------------------------------------------------------------------------
// zero_h: zero h1'/h2' each launch (payload-validation determinism).
// Agent-scope dword stores (write-through; no dirty local-L2 lines).
// ---------------------------------------------------------------------------
__global__ void __launch_bounds__(256) zero_h(unsigned int* __restrict__ h1,
                                              unsigned int* __restrict__ h2) {
    int blk = blockIdx.x;
    unsigned int* dst = (blk < 256) ? h1 : h2;
    int base = ((blk & 255) * 256 + threadIdx.x) * 4;
    #pragma unroll
    for (int i = 0; i < 4; ++i)
        __hip_atomic_store(dst + base + i, 0u, __ATOMIC_RELAXED, __HIP_MEMORY_SCOPE_AGENT);
}

// ---------------------------------------------------------------------------
// pack_rec: weight fragment streams (all-gates-per-wave cols: col=dloc*4+gate)
// A chunks 0..511:   chunk = slot*8+kb (slot 0..63), src=Whh1
// B chunks 512..1535: chunk = 512+slot2*8+kb (slot2 0..127; sl=slot2>>1,
//                     mat=slot2&1; src = mat? Whh2 : Wih2)
// Also accumulates corr = 3*rowsum(w_hi+w_lo) per (slot,col) via f32 atomics.
// ---------------------------------------------------------------------------
__global__ void __launch_bounds__(256) pack_rec(const float* __restrict__ Whh1,
                                                const float* __restrict__ Wih2,
                                                const float* __restrict__ Whh2,
                                                unsigned short* __restrict__ Wpk_hi,
                                                unsigned short* __restrict__ Wpk_lo,
                                                float* __restrict__ corrA,
                                                float* __restrict__ corrB) {
    int ct = blockIdx.x * 256 + threadIdx.x;   // 1536 chunks x 64 lanes
    int chunk = ct >> 6, lane = ct & 63;
    int c = lane & 15, kh = lane >> 4;
    int gate = c & 3, dloc = c >> 2;
    const float* src;
    int grow, k0;
    float* corrp;
    if (chunk < 512) {
        int slot = chunk >> 3, kb = chunk & 7;
        grow = gate * 256 + slot * 4 + dloc;
        k0 = kb * 32 + kh * 8;
        src = Whh1;
        corrp = corrA + slot * 16 + c;
    } else {
        int cc = chunk - 512;
        int slot2 = cc >> 3, kb = cc & 7;
        int sl = slot2 >> 1, mat = slot2 & 1;
        grow = gate * 256 + sl * 4 + dloc;
        k0 = kb * 32 + kh * 8;
        src = mat ? Whh2 : Wih2;
        corrp = corrB + slot2 * 16 + c;
    }
    const float* sp = src + (size_t)grow * 256 + k0;
    bf16x8 hi, lo;
    float rsum = 0.f;
    for (int j = 0; j < 8; ++j) {
        float v = sp[j];
        unsigned short h = f2bf(v);
        float hf = bf2f(h);
        unsigned short l = f2bf(v - hf);
        hi[j] = (short)h;
        lo[j] = (short)l;
        rsum += hf + bf2f(l);
    }
    size_t o = (size_t)ct * 8;
    *reinterpret_cast<bf16x8*>(Wpk_hi + o) = hi;
    *reinterpret_cast<bf16x8*>(Wpk_lo + o) = lo;
    atomicAdd(corrp, 3.f * rsum);
}

// ---------------------------------------------------------------------------
// pack_w1: Wih1 -> bf16 hi/lo fragment stream. Block 128: alpha cumprod.
// ---------------------------------------------------------------------------
__global__ void __launch_bounds__(256) pack_w1(const float* __restrict__ Wih1,
                                               unsigned short* __restrict__ W1h,
                                               unsigned short* __restrict__ W1l,
                                               const float* __restrict__ betas,
                                               const int* __restrict__ dift,
                                               float* __restrict__ alpha) {
    if (blockIdx.x == 128) {
        int tid = threadIdx.x;
        if (tid < 32) {
            int tb = dift[tid];
            float p = 1.f;
            for (int i = 0; i <= tb; ++i) p *= (1.f - betas[i]);
            alpha[tid] = p;
        }
        return;
    }
    int c = blockIdx.x * 256 + threadIdx.x;
    int nt = c >> 9;
    int r = c & 511;
    int kb = r >> 6;
    int lane = r & 63;
    int grow = nt * 16 + (lane & 15);
    int k0 = kb * 32 + (lane >> 4) * 8;
    const float* sp = Wih1 + (size_t)grow * 256 + k0;
    bf16x8 hi, lo;
    for (int j = 0; j < 8; ++j) {
        float v = sp[j];
        unsigned short h = f2bf(v);
        hi[j] = (short)h;
        lo[j] = (short)f2bf(v - bf2f(h));
    }
    size_t o = (size_t)c * 8;
    *reinterpret_cast<bf16x8*>(W1h + o) = hi;
    *reinterpret_cast<bf16x8*>(W1l + o) = lo;
}

// ---------------------------------------------------------------------------
// attn_bags (unchanged, verified)
// ---------------------------------------------------------------------------
__global__ void __launch_bounds__(256) attn_bags(
    const int* __restrict__ seqs, const float* __restrict__ tstep,
    const float* __restrict__ cmask, const float* __restrict__ emb,
    const float* __restrict__ decay, const float* __restrict__ initial,
    const unsigned short* __restrict__ M_pk, float* __restrict__ vv) {
    __shared__ __align__(16) unsigned short x_bf[32 * 256];
    __shared__ __align__(16) unsigned short t1_bf[32 * 256];
    __shared__ float dp_f[32 * 33];
    __shared__ float gate_sh[32];
    __shared__ float cm_sh[32];
    __shared__ int tok_sh[32];
    __shared__ float w_sh[32];

    int bag = blockIdx.x;
    int tid = threadIdx.x;

    if (tid < 32) {
        int tok = seqs[bag * 32 + tid];
        tok_sh[tid] = tok;
        float cm = cmask[bag * 32 + tid];
        cm_sh[tid] = cm;
        float tt = tstep[bag];
        float g = sigm(decay[tok] * tt + initial[tok]);
        g *= (cm - 1e20f) / (-1e20f);
        gate_sh[tid] = g;
    }
    __syncthreads();

    for (int it = 0; it < 8; ++it) {
        int fidx = it * 256 + tid;
        int c = fidx >> 6;
        int f4 = fidx & 63;
        const float4* src = reinterpret_cast<const float4*>(emb + (size_t)tok_sh[c] * 256) + f4;
        float4 vx = *src;
        int colx = f4 * 4;
        int eidx = c * 256 + (colx ^ ((c & 7) << 3));
        ushort4 w;
        w.x = f2bf(vx.x); w.y = f2bf(vx.y); w.z = f2bf(vx.z); w.w = f2bf(vx.w);
        *reinterpret_cast<ushort4*>(&x_bf[eidx]) = w;
    }
    __syncthreads();

    int wv = tid >> 6;
    int lane = tid & 63;
    int lr = lane & 15;
    int lk = lane >> 4;

    f32x4 acc[2][4];
    for (int a = 0; a < 2; ++a)
        for (int n = 0; n < 4; ++n) acc[a][n] = (f32x4){0.f, 0.f, 0.f, 0.f};
    for (int kb = 0; kb < 8; ++kb) {
        bf16x8 afr[2];
        for (int mb = 0; mb < 2; ++mb) {
            int row = mb * 16 + lr;
            int colx = kb * 32 + lk * 8;
            afr[mb] = *reinterpret_cast<const bf16x8*>(&x_bf[row * 256 + (colx ^ ((row & 7) << 3))]);
        }
        for (int nbi = 0; nbi < 4; ++nbi) {
            int nb = wv * 4 + nbi;
            bf16x8 bfr = *reinterpret_cast<const bf16x8*>(M_pk + (((nb * 8 + kb) * 64) + lane) * 8);
            acc[0][nbi] = __builtin_amdgcn_mfma_f32_16x16x32_bf16(afr[0], bfr, acc[0][nbi], 0, 0, 0);
            acc[1][nbi] = __builtin_amdgcn_mfma_f32_16x16x32_bf16(afr[1], bfr, acc[1][nbi], 0, 0, 0);
        }
    }
    for (int mb = 0; mb < 2; ++mb)
        for (int nbi = 0; nbi < 4; ++nbi)
            for (int r = 0; r < 4; ++r) {
                int row = mb * 16 + lk * 4 + r;
                int colx = wv * 64 + nbi * 16 + lr;
                t1_bf[row * 256 + (colx ^ ((row & 7) << 3))] = f2bf(acc[mb][nbi][r]);
            }
    __syncthreads();

    {
        int mb = wv >> 1, nb2 = wv & 1;
        f32x4 dacc = (f32x4){0.f, 0.f, 0.f, 0.f};
        for (int kb = 0; kb < 8; ++kb) {
            int cola = kb * 32 + lk * 8;
            int rowa = mb * 16 + lr;
            bf16x8 afr = *reinterpret_cast<const bf16x8*>(&t1_bf[rowa * 256 + (cola ^ ((rowa & 7) << 3))]);
            int rowb = nb2 * 16 + lr;
            bf16x8 bfr = *reinterpret_cast<const bf16x8*>(&x_bf[rowb * 256 + (cola ^ ((rowb & 7) << 3))]);
            dacc = __builtin_amdgcn_mfma_f32_16x16x32_bf16(afr, bfr, dacc, 0, 0, 0);
        }
        for (int r = 0; r < 4; ++r) {
            int c = mb * 16 + lk * 4 + r;
            int e = nb2 * 16 + lr;
            dp_f[c * 33 + e] = dacc[r];
        }
    }
    __syncthreads();

    if (tid < 32) {
        int c = tid;
        float cmc = cm_sh[c];
        float lg[32];
        float mx = -1e30f;
        for (int e = 0; e < 32; ++e) {
            float l = (dp_f[c * 33 + e] - cmc - cm_sh[e]) * 0.0625f;
            lg[e] = l;
            mx = fmaxf(mx, l);
        }
        float s = 0.f;
        for (int e = 0; e < 32; ++e) { float ex = __expf(lg[e] - mx); lg[e] = ex; s += ex; }
        float inv = 1.f / s;
        for (int e = 0; e < 32; ++e) dp_f[c * 33 + e] = lg[e] * inv;
    }
    __syncthreads();
    if (tid < 32) {
        int e = tid;
        float a2 = 0.f;
        for (int c = 0; c < 32; ++c) a2 += gate_sh[c] * dp_f[c * 33 + e];
        w_sh[e] = a2;
    }
    __syncthreads();

    float accv = 0.f;
    int d = tid;
    for (int e = 0; e < 32; ++e)
        accv += w_sh[e] * bf2f(x_bf[e * 256 + (d ^ ((e & 7) << 3))]);
    vv[(size_t)bag * 256 + d] = accv;
}

// ---------------------------------------------------------------------------
// x1_mfma: X1bf[t][b][d][gate] = bf16( vv @ Wih1^T + lstm_b )
// ---------------------------------------------------------------------------
__global__ void __launch_bounds__(256) x1_mfma(const float* __restrict__ vv,
                                               const unsigned short* __restrict__ W1h,
                                               const unsigned short* __restrict__ W1l,
                                               const float* __restrict__ lstm_b,
                                               unsigned short* __restrict__ X1bf) {
    __shared__ __align__(16) unsigned short xs[32 * 256];
    int blk = blockIdx.x;
    int rb = blk >> 3, gb = blk & 7;
    int tid = threadIdx.x;
    for (int it = 0; it < 8; ++it) {
        int idx = it * 256 + tid;
        int row = idx >> 6, f4 = idx & 63;
        float4 v = *reinterpret_cast<const float4*>(vv + (size_t)(rb * 32 + row) * 256 + f4 * 4);
        ushort4 w;
        w.x = f2bf(v.x); w.y = f2bf(v.y); w.z = f2bf(v.z); w.w = f2bf(v.w);
        *reinterpret_cast<ushort4*>(&xs[row * 256 + ((f4 * 4) ^ ((row & 7) << 3))]) = w;
    }
    __syncthreads();
    int wv = tid >> 6, lane = tid & 63, cl = lane & 15, kh = lane >> 4;
    f32x4 acc[2][2];
    for (int n = 0; n < 2; ++n) {
        int nt = gb * 8 + wv * 2 + n;
        float bz = lstm_b[nt * 16 + cl];
        acc[n][0] = (f32x4){bz, bz, bz, bz};
        acc[n][1] = (f32x4){bz, bz, bz, bz};
    }
    #pragma unroll
    for (int kb = 0; kb < 8; ++kb) {
        int k = kb * 32 + kh * 8;
        bf16x8 a0 = *reinterpret_cast<const bf16x8*>(&xs[cl * 256 + (k ^ ((cl & 7) << 3))]);
        bf16x8 a1 = *reinterpret_cast<const bf16x8*>(&xs[(16 + cl) * 256 + (k ^ (((16 + cl) & 7) << 3))]);
        for (int n = 0; n < 2; ++n) {
            int nt = gb * 8 + wv * 2 + n;
            size_t o = ((size_t)(nt * 8 + kb) * 64 + lane) * 8;
            bf16x8 bh = *reinterpret_cast<const bf16x8*>(W1h + o);
            bf16x8 bl = *reinterpret_cast<const bf16x8*>(W1l + o);
            acc[n][0] = __builtin_amdgcn_mfma_f32_16x16x32_bf16(a0, bh, acc[n][0], 0, 0, 0);
            acc[n][0] = __builtin_amdgcn_mfma_f32_16x16x32_bf16(a0, bl, acc[n][0], 0, 0, 0);
            acc[n][1] = __builtin_amdgcn_mfma_f32_16x16x32_bf16(a1, bh, acc[n][1], 0, 0, 0);
            acc[n][1] = __builtin_amdgcn_mfma_f32_16x16x32_bf16(a1, bl, acc[n][1], 0, 0, 0);
        }
    }
    for (int n = 0; n < 2; ++n) {
        int nt = gb * 8 + wv * 2 + n;
        int g = nt * 16 + cl;
        int dX = g & 255, gt = g >> 8;
        for (int mt = 0; mt < 2; ++mt)
            for (int r = 0; r < 4; ++r) {
                int row = rb * 32 + mt * 16 + kh * 4 + r;
                int b = row >> 6, t = row & 63;
                X1bf[((size_t)t * 32 + b) * 1024 + dX * 4 + gt] = f2bf(acc[n][mt][r]);
            }
    }
}

// ---------------------------------------------------------------------------
// lstm_persist: flag-free payload-validated pipeline. 48 wgs.
// h stored as h' = h+3 (bf16 in (2,4)); readiness = high byte 0x40.
// A (wgs 0..15): all-gates-per-wave, no LDS. slot=wg*4+wv, d=slot*4+dloc.
// B (wgs 16..47): mat-split (wv even: Wih2*h1[s]; wv odd: Whh2*h2[s-1]),
//   LDS zbuf combine. GEMM shift folded via corr = 3*rowsum(W).
// ---------------------------------------------------------------------------
__global__ void __launch_bounds__(256, 1) lstm_persist(
    const unsigned short* __restrict__ Wpk_hi, const unsigned short* __restrict__ Wpk_lo,
    const unsigned short* __restrict__ X1bf, const float* __restrict__ hs_b,
    const float* __restrict__ corrA, const float* __restrict__ corrB,
    unsigned short* h1, unsigned short* h2) {
    int wg = blockIdx.x, tid = threadIdx.x;
    int wv = tid >> 6, lane = tid & 63;
    int c = lane & 15, grp = lane >> 4;
    int q = c & 3, dloc = c >> 2;
    bool isA = wg < 16;

    if (isA) {
        int slot = wg * 4 + wv;
        int d = slot * 4 + dloc;
        int b0 = grp * 4 + q;
        bf16x8 wh[8], wl[8];
        #pragma unroll
        for (int kb = 0; kb < 8; ++kb) {
            size_t o = ((size_t)(slot * 8 + kb) * 64 + lane) * 8;
            wh[kb] = *reinterpret_cast<const bf16x8*>(Wpk_hi + o);
            wl[kb] = *reinterpret_cast<const bf16x8*>(Wpk_lo + o);
        }
        float corrv = corrA[slot * 16 + c];
        float cst0 = 0.f, cst1 = 0.f;
        for (int p = 0; p < 64; ++p) {
            ushort4 x1v0 = *reinterpret_cast<const ushort4*>(
                X1bf + (((size_t)p * 32 + b0) * 256 + d) * 4);
            ushort4 x1v1 = *reinterpret_cast<const ushort4*>(
                X1bf + (((size_t)p * 32 + b0 + 16) * 256 + d) * 4);
            f32x4 acc0 = (f32x4){0.f, 0.f, 0.f, 0.f};
            f32x4 acc1 = acc0;
            if (p > 0) {
                acc0 = (f32x4){-corrv, -corrv, -corrv, -corrv};
                acc1 = acc0;
                const unsigned short* hB = h1 + (size_t)(p - 1) * 8192;
                bf16x8 a0[8], a1[8];
                while (true) {
                    #pragma unroll
                    for (int kb = 0; kb < 8; ++kb) {
                        a0[kb] = ldg_sc(hB + c * 256 + kb * 32 + grp * 8);
                        a1[kb] = ldg_sc(hB + (16 + c) * 256 + kb * 32 + grp * 8);
                    }
                    asm volatile("s_waitcnt vmcnt(0)" ::: "memory");
                    __builtin_amdgcn_sched_barrier(0);
                    unsigned int bad = 0;
                    #pragma unroll
                    for (int kb = 0; kb < 8; ++kb)
                        bad |= frag_bad(a0[kb]) | frag_bad(a1[kb]);
                    if (__all(bad == 0)) break;
                    __builtin_amdgcn_s_sleep(2);
                }
                __builtin_amdgcn_sched_barrier(0);
                #pragma unroll
                for (int kb = 0; kb < 8; ++kb) {
                    acc0 = __builtin_amdgcn_mfma_f32_16x16x32_bf16(a0[kb], wh[kb], acc0, 0, 0, 0);
                    acc0 = __builtin_amdgcn_mfma_f32_16x16x32_bf16(a0[kb], wl[kb], acc0, 0, 0, 0);
                    acc1 = __builtin_amdgcn_mfma_f32_16x16x32_bf16(a1[kb], wh[kb], acc1, 0, 0, 0);
                    acc1 = __builtin_amdgcn_mfma_f32_16x16x32_bf16(a1[kb], wl[kb], acc1, 0, 0, 0);
                }
            }
            float za[4] = {acc0[0], acc0[1], acc0[2], acc0[3]};
            float zb[4] = {acc1[0], acc1[1], acc1[2], acc1[3]};
            tr4(za, q);
            tr4(zb, q);
            float zi = za[0] + bf2f(x1v0.x);
            float zf = za[1] + bf2f(x1v0.y);
            float zg = za[2] + bf2f(x1v0.z);
            float zo = za[3] + bf2f(x1v0.w);
            float cn0 = sigm_f(zf) * cst0 + sigm_f(zi) * tanh_f(zg);
            float hn0 = sigm_f(zo) * tanh_f(cn0);
            cst0 = cn0;
            zi = zb[0] + bf2f(x1v1.x);
            zf = zb[1] + bf2f(x1v1.y);
            zg = zb[2] + bf2f(x1v1.z);
            zo = zb[3] + bf2f(x1v1.w);
            float cn1 = sigm_f(zf) * cst1 + sigm_f(zi) * tanh_f(zg);
            float hn1 = sigm_f(zo) * tanh_f(cn1);
            cst1 = cn1;
            unsigned int pk0 = f2bf(hn0 + 3.f), pk1 = f2bf(hn1 + 3.f);
            unsigned int pr0 = (unsigned int)__shfl_xor((int)pk0, 4);
            unsigned int pr1 = (unsigned int)__shfl_xor((int)pk1, 4);
            if ((c & 4) == 0) {
                __hip_atomic_store((unsigned int*)h1 + ((((size_t)p * 32 + b0) * 256 + d) >> 1),
                                   pk0 | (pr0 << 16), __ATOMIC_RELAXED, __HIP_MEMORY_SCOPE_AGENT);
                __hip_atomic_store((unsigned int*)h1 + ((((size_t)p * 32 + b0 + 16) * 256 + d) >> 1),
                                   pk1 | (pr1 << 16), __ATOMIC_RELAXED, __HIP_MEMORY_SCOPE_AGENT);
            }
            // no drain, no flag: payload IS the signal
        }
    } else {
        __shared__ float zbuf[4][16][33];
        int slot2 = (wg - 16) * 4 + wv;         // 0..127
        int mat = slot2 & 1;                    // 0: Wih2*h1[s], 1: Whh2*h2[s-1]
        bf16x8 wh[8], wl[8];
        #pragma unroll
        for (int kb = 0; kb < 8; ++kb) {
            size_t o = ((size_t)(512 + slot2 * 8 + kb) * 64 + lane) * 8;
            wh[kb] = *reinterpret_cast<const bf16x8*>(Wpk_hi + o);
            wl[kb] = *reinterpret_cast<const bf16x8*>(Wpk_lo + o);
        }
        float corrv = corrB[slot2 * 16 + c];
        // recombine-thread mapping
        int bR = tid & 31;
        int idx = tid >> 5;                     // 0..7
        int sl_loc = idx >> 2, dlocR = idx & 3;
        int dG = ((wg - 16) * 2 + sl_loc) * 4 + dlocR;
        float bias[4];
        #pragma unroll
        for (int g = 0; g < 4; ++g) bias[g] = hs_b[g * 256 + dG];
        float cst = 0.f;
        for (int s = 0; s < 64; ++s) {
            f32x4 acc0 = (f32x4){0.f, 0.f, 0.f, 0.f};
            f32x4 acc1 = acc0;
            bool active = (mat == 0) || (s > 0);
            if (active) {
                acc0 = (f32x4){-corrv, -corrv, -corrv, -corrv};
                acc1 = acc0;
                const unsigned short* hB =
                    (mat == 0) ? (h1 + (size_t)s * 8192) : (h2 + (size_t)(s - 1) * 8192);
                bf16x8 a0[8], a1[8];
                while (true) {
                    #pragma unroll
                    for (int kb = 0; kb < 8; ++kb) {
                        a0[kb] = ldg_sc(hB + c * 256 + kb * 32 + grp * 8);
                        a1[kb] = ldg_sc(hB + (16 + c) * 256 + kb * 32 + grp * 8);
                    }
                    asm volatile("s_waitcnt vmcnt(0)" ::: "memory");
                    __builtin_amdgcn_sched_barrier(0);
                    unsigned int bad = 0;
                    #pragma unroll
                    for (int kb = 0; kb < 8; ++kb)
                        bad |= frag_bad(a0[kb]) | frag_bad(a1[kb]);
                    if (__all(bad == 0)) break;
                    __builtin_amdgcn_s_sleep(2);
                }
                __builtin_amdgcn_sched_barrier(0);
                #pragma unroll
                for (int kb = 0; kb < 8; ++kb) {
                    acc0 = __builtin_amdgcn_mfma_f32_16x16x32_bf16(a0[kb], wh[kb], acc0, 0, 0, 0);
                    acc0 = __builtin_amdgcn_mfma_f32_16x16x32_bf16(a0[kb], wl[kb], acc0, 0, 0, 0);
                    acc1 = __builtin_amdgcn_mfma_f32_16x16x32_bf16(a1[kb], wh[kb], acc1, 0, 0, 0);
                    acc1 = __builtin_amdgcn_mfma_f32_16x16x32_bf16(a1[kb], wl[kb], acc1, 0, 0, 0);
                }
            }
            __syncthreads();   // zbuf from previous step fully consumed
            #pragma unroll
            for (int r = 0; r < 4; ++r) {
                zbuf[wv][c][grp * 4 + r] = acc0[r];
                zbuf[wv][c][16 + grp * 4 + r] = acc1[r];
            }
            __syncthreads();
            float z[4];
            #pragma unroll
            for (int g = 0; g < 4; ++g)
                z[g] = zbuf[2 * sl_loc][dlocR * 4 + g][bR] +
                       zbuf[2 * sl_loc + 1][dlocR * 4 + g][bR] + bias[g];
            float cn = sigm_f(z[1]) * cst + sigm_f(z[0]) * tanh_f(z[2]);
            float hn = sigm_f(z[3]) * tanh_f(cn);
            cst = cn;
            unsigned int pk = f2bf(hn + 3.f);
            unsigned int pr = (unsigned int)__shfl_xor((int)pk, 32);
            if ((idx & 1) == 0)
                __hip_atomic_store((unsigned int*)h2 + ((((size_t)s * 32 + bR) * 256 + dG) >> 1),
                                   pk | (pr << 16), __ATOMIC_RELAXED, __HIP_MEMORY_SCOPE_AGENT);
        }
    }
}

// ---------------------------------------------------------------------------
// tail_k: per batch, only row v* = lengths[b]-1 matters. h decode: -3.
// ---------------------------------------------------------------------------
__global__ void __launch_bounds__(256) tail_k(
    const int* __restrict__ lengths,
    const unsigned short* __restrict__ h1, const unsigned short* __restrict__ h2,
    const float* __restrict__ whk_W, const float* __restrict__ whk_b,
    const float* __restrict__ w1_W, const float* __restrict__ w1_b,
    const float* __restrict__ w2_W, const float* __restrict__ w2_b,
    const float* __restrict__ fuse_W, const float* __restrict__ fuse_b,
    const float* __restrict__ lab_W, const float* __restrict__ lab_b,
    const float* __restrict__ Wdiff, const float* __restrict__ alpha,
    const float* __restrict__ noise, float* __restrict__ out) {
    __shared__ float ek[256], tv[256], hs[256], whp[256], a1s[64];
    __shared__ float noisy_s[256], fin[512], fused_s[256], attn_s[2];
    int b = blockIdx.x, tid = threadIdx.x;
    int vstar = lengths[b] - 1;
    {
        ek[tid] = bf2f(h1[(size_t)b * 256 + tid]) - 3.f;
        tv[tid] = bf2f(h1[((size_t)vstar * 32 + b) * 256 + tid]) - 3.f;
        if (vstar > 0)
            hs[tid] = bf2f(h2[((size_t)(vstar - 1) * 32 + b) * 256 + tid]) - 3.f;
    }
    __syncthreads();

    float aligned;
    if (vstar > 0) {
        float acc = whk_b[tid];
        const float4* wr4 = reinterpret_cast<const float4*>(whk_W + (size_t)tid * 256);
        #pragma unroll 8
        for (int k4 = 0; k4 < 64; ++k4) {
            float4 w = wr4[k4];
            acc += w.x * hs[k4 * 4] + w.y * hs[k4 * 4 + 1] + w.z * hs[k4 * 4 + 2] + w.w * hs[k4 * 4 + 3];
        }
        whp[tid] = acc;
        __syncthreads();
        if (tid < 64) {
            float a2 = w1_b[tid];
            const float4* wr14 = reinterpret_cast<const float4*>(w1_W + (size_t)tid * 512);
            #pragma unroll 8
            for (int k4 = 0; k4 < 64; ++k4) {
                float4 w = wr14[k4];
                a2 += w.x * ek[k4 * 4] + w.y * ek[k4 * 4 + 1] + w.z * ek[k4 * 4 + 2] + w.w * ek[k4 * 4 + 3];
            }
            #pragma unroll 8
            for (int k4 = 0; k4 < 64; ++k4) {
                float4 w = wr14[64 + k4];
                a2 += w.x * whp[k4 * 4] + w.y * whp[k4 * 4 + 1] + w.z * whp[k4 * 4 + 2] + w.w * whp[k4 * 4 + 3];
            }
            a1s[tid] = tanhf(a2);
        }
        __syncthreads();
        if (tid < 2) {
            float a3 = w2_b[tid];
            const float* wr2 = w2_W + tid * 64;
            for (int k = 0; k < 64; ++k) a3 += wr2[k] * a1s[k];
            attn_s[tid] = a3;
        }
        __syncthreads();
        float m = fmaxf(attn_s[0], attn_s[1]);
        float e0 = __expf(attn_s[0] - m), e1 = __expf(attn_s[1] - m);
        float inv = 1.f / (e0 + e1);
        aligned = ek[tid] * (e0 * inv) + whp[tid] * (e1 * inv);
    } else {
        aligned = ek[tid];
    }

    float al = alpha[b];
    float sa = sqrtf(al), sb = sqrtf(1.f - al);
    float nz = noise[((size_t)b * 64 + vstar) * 256 + tid];
    noisy_s[tid] = aligned * sa + nz * sb;
    __syncthreads();
    float pn = 0.f;
    for (int k = 0; k < 256; ++k) pn += noisy_s[k] * Wdiff[(size_t)k * 256 + tid];
    float gen = aligned + nz - pn;
    fin[tid] = tv[tid];
    fin[256 + tid] = gen;
    __syncthreads();
    float fu = fuse_b[tid];
    const float4* fw4 = reinterpret_cast<const float4*>(fuse_W + (size_t)tid * 512);
    #pragma unroll 8
    for (int k4 = 0; k4 < 128; ++k4) {
        float4 w = fw4[k4];
        fu += w.x * fin[k4 * 4] + w.y * fin[k4 * 4 + 1] + w.z * fin[k4 * 4 + 2] + w.w * fin[k4 * 4 + 3];
    }
    fused_s[tid] = fu;
    __syncthreads();
    if (tid < 2) {
        float o = lab_b[tid];
        const float* lw = lab_W + tid * 256;
        for (int k = 0; k < 256; ++k) o += lw[k] * fused_s[k];
        out[b * 2 + tid] = o;
    }
}

// ---------------------------------------------------------------------------
extern "C" void kernel_launch(void* const* d_in, const int* in_sizes, int n_in,
                              void* d_out, int out_size, void* d_ws, size_t ws_size,
                              hipStream_t stream) {
    const int*   seqs    = (const int*)  d_in[0];
    const int*   lengths = (const int*)  d_in[2];
    const float* tstep   = (const float*)d_in[3];
    const float* cmask   = (const float*)d_in[4];
    const float* emb     = (const float*)d_in[5];
    const float* WQ1     = (const float*)d_in[6];
    const float* WK1     = (const float*)d_in[7];
    const float* decay   = (const float*)d_in[8];
    const float* initial = (const float*)d_in[9];
    const float* Wih1    = (const float*)d_in[10];
    const float* Whh1    = (const float*)d_in[11];
    const float* lstm_b  = (const float*)d_in[12];
    const float* Wih2    = (const float*)d_in[13];
    const float* Whh2    = (const float*)d_in[14];
    const float* hs_b    = (const float*)d_in[15];
    const float* whk_W   = (const float*)d_in[16];
    const float* whk_b   = (const float*)d_in[17];
    const float* w1_W    = (const float*)d_in[18];
    const float* w1_b    = (const float*)d_in[19];
    const float* w2_W    = (const float*)d_in[20];
    const float* w2_b    = (const float*)d_in[21];
    const float* fuse_W  = (const float*)d_in[22];
    const float* fuse_b  = (const float*)d_in[23];
    const float* lab_W   = (const float*)d_in[24];
    const float* lab_b   = (const float*)d_in[25];
    const float* betas   = (const float*)d_in[26];
    const float* Wdiff   = (const float*)d_in[27];
    const int*   dift    = (const int*)  d_in[28];
    const float* noise   = (const float*)d_in[29];
    float* out = (float*)d_out;

    float* ws = (float*)d_ws;
    size_t off = 0;
    auto alloc = [&](size_t nfloats) { size_t r = off; off += (nfloats + 63) & ~(size_t)63; return r; };
    unsigned short* M_pk   = (unsigned short*)(ws + alloc(32768));
    float*          alpha  = ws + alloc(64);
    float*          corrA  = ws + alloc(1024);
    float*          corrB  = ws + alloc(2048);
    float*          vv     = ws + alloc(524288);
    unsigned short* X1bf   = (unsigned short*)(ws + alloc(1048576));  // 64*32*1024 u16
    unsigned short* h1     = (unsigned short*)(ws + alloc(262144));   // 64*32*256 u16 (1 MB)
    unsigned short* h2     = (unsigned short*)(ws + alloc(262144));
    unsigned short* Wpk_hi = (unsigned short*)(ws + alloc(393216));   // 1536 chunks * 512 u16
    unsigned short* Wpk_lo = (unsigned short*)(ws + alloc(393216));
    unsigned short* W1h    = (unsigned short*)(ws + alloc(131072));
    unsigned short* W1l    = (unsigned short*)(ws + alloc(131072));

    prep_M<<<65, 256, 0, stream>>>(WQ1, WK1, M_pk, corrA, corrB);
    zero_h<<<512, 256, 0, stream>>>((unsigned int*)h1, (unsigned int*)h2);
    pack_rec<<<384, 256, 0, stream>>>(Whh1, Wih2, Whh2, Wpk_hi, Wpk_lo, corrA, corrB);
    pack_w1<<<129, 256, 0, stream>>>(Wih1, W1h, W1l, betas, dift, alpha);
    attn_bags<<<2048, 256, 0, stream>>>(seqs, tstep, cmask, emb, decay, initial, M_pk, vv);
    x1_mfma<<<512, 256, 0, stream>>>(vv, W1h, W1l, lstm_b, X1bf);
    lstm_persist<<<48, 256, 0, stream>>>(Wpk_hi, Wpk_lo, X1bf, hs_b, corrA, corrB, h1, h2);
    tail_k<<<32, 256, 0, stream>>>(lengths, h1, h2, whk_W, whk_b,
                                   w1_W, w1_b, w2_W, w2_b, fuse_W, fuse_b,
                                   lab_W, lab_b, Wdiff, alpha, noise, out);
}

// Round 6
// 575.990 us; speedup vs baseline: 1.1484x; 1.1484x over previous
//
#include <hip/hip_runtime.h>
#include <hip/hip_bf16.h>
#include <cmath>

typedef __attribute__((ext_vector_type(8))) short bf16x8;
typedef __attribute__((ext_vector_type(4))) float f32x4;

__device__ __forceinline__ float bf2f(unsigned short u) {
    unsigned int x = ((unsigned int)u) << 16;
    return __builtin_bit_cast(float, x);
}
__device__ __forceinline__ unsigned short f2bf(float f) {
    unsigned int x = __builtin_bit_cast(unsigned int, f);
    unsigned int lsb = (x >> 16) & 1u;
    x += 0x7fffu + lsb;
    return (unsigned short)(x >> 16);
}
__device__ __forceinline__ float sigm(float z) {
    return 1.f / (1.f + __expf(-z));
}
__device__ __forceinline__ float rcpf(float x) { return __builtin_amdgcn_rcpf(x); }
__device__ __forceinline__ float sigm_f(float z) { return rcpf(1.f + __expf(-z)); }
__device__ __forceinline__ float tanh_f(float z) { return 1.f - 2.f * rcpf(1.f + __expf(2.f * z)); }

// Agent-coherent 16B load (bypasses non-coherent local caches -> IF$).
__device__ __forceinline__ bf16x8 ldg_sc(const unsigned short* p) {
    bf16x8 r;
    asm volatile("global_load_dwordx4 %0, %1, off sc1"
                 : "=v"(r) : "v"(p) : "memory");
    return r;
}

// h' = h+3 in (2,4): every bf16 high byte == 0x40. Returns 0 iff valid.
__device__ __forceinline__ unsigned int frag_bad(bf16x8 v) {
    uint4 u = __builtin_bit_cast(uint4, v);
    return ((u.x & 0xFF00FF00u) ^ 0x40004000u) |
           ((u.y & 0xFF00FF00u) ^ 0x40004000u) |
           ((u.z & 0xFF00FF00u) ^ 0x40004000u) |
           ((u.w & 0xFF00FF00u) ^ 0x40004000u);
}

// in-quad 4x4 transpose (lane q holds M[q][:]; after: a[g] = M[g][q]).
__device__ __forceinline__ void tr4(float a[4], int q) {
    float u0 = (q & 1) ? a[0] : a[1];
    float u1 = (q & 1) ? a[2] : a[3];
    float v0 = __shfl_xor(u0, 1);
    float v1 = __shfl_xor(u1, 1);
    if (q & 1) { a[0] = v0; a[2] = v1; } else { a[1] = v0; a[3] = v1; }
    float w0 = (q & 2) ? a[0] : a[2];
    float w1 = (q & 2) ? a[1] : a[3];
    float s0 = __shfl_xor(w0, 2);
    float s1 = __shfl_xor(w1, 2);
    if (q & 2) { a[0] = s0; a[1] = s1; } else { a[2] = s0; a[3] = s1; }
}

// ---------------------------------------------------------------------------
// pack_all: every prep task, block-range dispatched.
//  [0,384)      pack_rec hi-only weight fragments (A: Whh1, B: Wih2/Whh2)
//  [384,512)    pack_w1 (Wih1 hi+lo fragments)
//  512          alpha cumprod
//  [513,525)    corrA/corrB = 3*rowsum(W_hi) per (slot, col)
//  [525,533)    zero flags (12288 ints)
//  [533,789)    zero h1/h2 (sc1 stores)
//  [789,853)    whkT transpose
//  [853,981)    fuseT transpose
//  [981,1013)   w1T transpose
//  [1013,1077)  prep_M (M = WQ1^T @ WK1, MFMA B-fragment order)
// ---------------------------------------------------------------------------
__global__ void __launch_bounds__(256) pack_all(
    const float* __restrict__ Whh1, const float* __restrict__ Wih2,
    const float* __restrict__ Whh2, const float* __restrict__ Wih1,
    const float* __restrict__ WQ1, const float* __restrict__ WK1,
    const float* __restrict__ betas, const int* __restrict__ dift,
    const float* __restrict__ whk_W, const float* __restrict__ fuse_W,
    const float* __restrict__ w1_W,
    unsigned short* __restrict__ Wpk_hi,
    unsigned short* __restrict__ W1h, unsigned short* __restrict__ W1l,
    unsigned short* __restrict__ M_pk,
    float* __restrict__ corrA, float* __restrict__ corrB,
    float* __restrict__ alpha, int* __restrict__ flags,
    unsigned int* __restrict__ h1u, unsigned int* __restrict__ h2u,
    float* __restrict__ whkT, float* __restrict__ fuseT,
    float* __restrict__ w1T) {
    int blk = blockIdx.x, tid = threadIdx.x;
    if (blk < 384) {
        // pack_rec (hi only)
        int ct = blk * 256 + tid;
        int chunk = ct >> 6, lane = ct & 63;
        int c = lane & 15, kh = lane >> 4;
        int gate = c & 3, dloc = c >> 2;
        const float* src;
        int grow, k0;
        if (chunk < 512) {
            int slot = chunk >> 3, kb = chunk & 7;
            grow = gate * 256 + slot * 4 + dloc;
            k0 = kb * 32 + kh * 8;
            src = Whh1;
        } else {
            int cc = chunk - 512;
            int slot2 = cc >> 3, kb = cc & 7;
            int sl = slot2 >> 1, mat = slot2 & 1;
            grow = gate * 256 + sl * 4 + dloc;
            k0 = kb * 32 + kh * 8;
            src = mat ? Whh2 : Wih2;
        }
        const float* sp = src + (size_t)grow * 256 + k0;
        bf16x8 hi;
        for (int j = 0; j < 8; ++j) hi[j] = (short)f2bf(sp[j]);
        *reinterpret_cast<bf16x8*>(Wpk_hi + (size_t)ct * 8) = hi;
    } else if (blk < 512) {
        // pack_w1 hi+lo
        int cch = (blk - 384) * 256 + tid;
        int nt = cch >> 9;
        int r = cch & 511;
        int kb = r >> 6;
        int lane = r & 63;
        int grow = nt * 16 + (lane & 15);
        int k0 = kb * 32 + (lane >> 4) * 8;
        const float* sp = Wih1 + (size_t)grow * 256 + k0;
        bf16x8 hi, lo;
        for (int j = 0; j < 8; ++j) {
            float v = sp[j];
            unsigned short h = f2bf(v);
            hi[j] = (short)h;
            lo[j] = (short)f2bf(v - bf2f(h));
        }
        size_t o = (size_t)cch * 8;
        *reinterpret_cast<bf16x8*>(W1h + o) = hi;
        *reinterpret_cast<bf16x8*>(W1l + o) = lo;
    } else if (blk == 512) {
        if (tid < 32) {
            int tb = dift[tid];
            float p = 1.f;
            for (int i = 0; i <= tb; ++i) p *= (1.f - betas[i]);
            alpha[tid] = p;
        }
    } else if (blk < 525) {
        // corr = 3 * rowsum(W_hi)
        int e = (blk - 513) * 256 + tid;   // 0..3071
        const float* src;
        int row;
        float* dst;
        if (e < 1024) {
            int slot = e >> 4, c = e & 15;
            row = (c & 3) * 256 + slot * 4 + (c >> 2);
            src = Whh1;
            dst = corrA + e;
        } else {
            int e2 = e - 1024;
            int slot2 = e2 >> 4, c = e2 & 15;
            int sl = slot2 >> 1, mat = slot2 & 1;
            row = (c & 3) * 256 + sl * 4 + (c >> 2);
            src = mat ? Whh2 : Wih2;
            dst = corrB + e2;
        }
        const float* sp = src + (size_t)row * 256;
        float s = 0.f;
        for (int k = 0; k < 256; ++k) s += bf2f(f2bf(sp[k]));
        *dst = 3.f * s;
    } else if (blk < 533) {
        int gid = (blk - 525) * 256 + tid;   // 0..2047
        for (int j = 0; j < 6; ++j) flags[j * 2048 + gid] = 0;
    } else if (blk < 789) {
        int gid = (blk - 533) * 256 + tid;   // 0..65535
        __hip_atomic_store(h1u + gid * 2, 0u, __ATOMIC_RELAXED, __HIP_MEMORY_SCOPE_AGENT);
        __hip_atomic_store(h1u + gid * 2 + 1, 0u, __ATOMIC_RELAXED, __HIP_MEMORY_SCOPE_AGENT);
        __hip_atomic_store(h2u + gid * 2, 0u, __ATOMIC_RELAXED, __HIP_MEMORY_SCOPE_AGENT);
        __hip_atomic_store(h2u + gid * 2 + 1, 0u, __ATOMIC_RELAXED, __HIP_MEMORY_SCOPE_AGENT);
    } else if (blk < 853) {
        int gid = (blk - 789) * 256 + tid;   // 0..16383
        for (int i = 0; i < 4; ++i) {
            int e = gid + i * 16384;
            int k = e >> 8, dd = e & 255;
            whkT[e] = whk_W[(size_t)dd * 256 + k];
        }
    } else if (blk < 981) {
        int gid = (blk - 853) * 256 + tid;   // 0..32767
        for (int i = 0; i < 4; ++i) {
            int e = gid + i * 32768;
            int k = e >> 8, dd = e & 255;
            fuseT[e] = fuse_W[(size_t)dd * 512 + k];
        }
    } else if (blk < 1013) {
        int gid = (blk - 981) * 256 + tid;   // 0..8191
        for (int i = 0; i < 4; ++i) {
            int e = gid + i * 8192;
            int k = e >> 6, j = e & 63;
            w1T[e] = w1_W[(size_t)j * 512 + k];
        }
    } else {
        // prep_M
        __shared__ unsigned short As[256][32];
        __shared__ unsigned short Bs[256][32];
        int bx = blk - 1013;
        int e0 = (bx >> 3) << 5;
        int f0 = (bx & 7) << 5;
        int col = tid & 31, rr = tid >> 5;
        for (int rep = 0; rep < 32; ++rep) {
            int d = rep * 8 + rr;
            As[d][col] = f2bf(WQ1[d * 256 + e0 + col]);
            Bs[d][col] = f2bf(WK1[d * 256 + f0 + col]);
        }
        __syncthreads();
        int el = tid & 31;
        int fl0 = tid >> 5;
        for (int i = 0; i < 4; ++i) {
            int fl = fl0 + 8 * i;
            float acc = 0.f;
            for (int d = 0; d < 256; ++d)
                acc += bf2f(As[d][el]) * bf2f(Bs[d][fl]);
            int e = e0 + el, f = f0 + fl;
            int kb = e >> 5, r = (e >> 3) & 3, j = e & 7;
            int nb = f >> 4;
            int lane = (r << 4) | (f & 15);
            M_pk[(((nb * 8 + kb) * 64) + lane) * 8 + j] = f2bf(acc);
        }
    }
}

// ---------------------------------------------------------------------------
// attn_bags (unchanged, verified)
// ---------------------------------------------------------------------------
__global__ void __launch_bounds__(256) attn_bags(
    const int* __restrict__ seqs, const float* __restrict__ tstep,
    const float* __restrict__ cmask, const float* __restrict__ emb,
    const float* __restrict__ decay, const float* __restrict__ initial,
    const unsigned short* __restrict__ M_pk, float* __restrict__ vv) {
    __shared__ __align__(16) unsigned short x_bf[32 * 256];
    __shared__ __align__(16) unsigned short t1_bf[32 * 256];
    __shared__ float dp_f[32 * 33];
    __shared__ float gate_sh[32];
    __shared__ float cm_sh[32];
    __shared__ int tok_sh[32];
    __shared__ float w_sh[32];

    int bag = blockIdx.x;
    int tid = threadIdx.x;

    if (tid < 32) {
        int tok = seqs[bag * 32 + tid];
        tok_sh[tid] = tok;
        float cm = cmask[bag * 32 + tid];
        cm_sh[tid] = cm;
        float tt = tstep[bag];
        float g = sigm(decay[tok] * tt + initial[tok]);
        g *= (cm - 1e20f) / (-1e20f);
        gate_sh[tid] = g;
    }
    __syncthreads();

    for (int it = 0; it < 8; ++it) {
        int fidx = it * 256 + tid;
        int c = fidx >> 6;
        int f4 = fidx & 63;
        const float4* src = reinterpret_cast<const float4*>(emb + (size_t)tok_sh[c] * 256) + f4;
        float4 vx = *src;
        int colx = f4 * 4;
        int eidx = c * 256 + (colx ^ ((c & 7) << 3));
        ushort4 w;
        w.x = f2bf(vx.x); w.y = f2bf(vx.y); w.z = f2bf(vx.z); w.w = f2bf(vx.w);
        *reinterpret_cast<ushort4*>(&x_bf[eidx]) = w;
    }
    __syncthreads();

    int wv = tid >> 6;
    int lane = tid & 63;
    int lr = lane & 15;
    int lk = lane >> 4;

    f32x4 acc[2][4];
    for (int a = 0; a < 2; ++a)
        for (int n = 0; n < 4; ++n) acc[a][n] = (f32x4){0.f, 0.f, 0.f, 0.f};
    for (int kb = 0; kb < 8; ++kb) {
        bf16x8 afr[2];
        for (int mb = 0; mb < 2; ++mb) {
            int row = mb * 16 + lr;
            int colx = kb * 32 + lk * 8;
            afr[mb] = *reinterpret_cast<const bf16x8*>(&x_bf[row * 256 + (colx ^ ((row & 7) << 3))]);
        }
        for (int nbi = 0; nbi < 4; ++nbi) {
            int nb = wv * 4 + nbi;
            bf16x8 bfr = *reinterpret_cast<const bf16x8*>(M_pk + (((nb * 8 + kb) * 64) + lane) * 8);
            acc[0][nbi] = __builtin_amdgcn_mfma_f32_16x16x32_bf16(afr[0], bfr, acc[0][nbi], 0, 0, 0);
            acc[1][nbi] = __builtin_amdgcn_mfma_f32_16x16x32_bf16(afr[1], bfr, acc[1][nbi], 0, 0, 0);
        }
    }
    for (int mb = 0; mb < 2; ++mb)
        for (int nbi = 0; nbi < 4; ++nbi)
            for (int r = 0; r < 4; ++r) {
                int row = mb * 16 + lk * 4 + r;
                int colx = wv * 64 + nbi * 16 + lr;
                t1_bf[row * 256 + (colx ^ ((row & 7) << 3))] = f2bf(acc[mb][nbi][r]);
            }
    __syncthreads();

    {
        int mb = wv >> 1, nb2 = wv & 1;
        f32x4 dacc = (f32x4){0.f, 0.f, 0.f, 0.f};
        for (int kb = 0; kb < 8; ++kb) {
            int cola = kb * 32 + lk * 8;
            int rowa = mb * 16 + lr;
            bf16x8 afr = *reinterpret_cast<const bf16x8*>(&t1_bf[rowa * 256 + (cola ^ ((rowa & 7) << 3))]);
            int rowb = nb2 * 16 + lr;
            bf16x8 bfr = *reinterpret_cast<const bf16x8*>(&x_bf[rowb * 256 + (cola ^ ((rowb & 7) << 3))]);
            dacc = __builtin_amdgcn_mfma_f32_16x16x32_bf16(afr, bfr, dacc, 0, 0, 0);
        }
        for (int r = 0; r < 4; ++r) {
            int c = mb * 16 + lk * 4 + r;
            int e = nb2 * 16 + lr;
            dp_f[c * 33 + e] = dacc[r];
        }
    }
    __syncthreads();

    if (tid < 32) {
        int c = tid;
        float cmc = cm_sh[c];
        float lg[32];
        float mx = -1e30f;
        for (int e = 0; e < 32; ++e) {
            float l = (dp_f[c * 33 + e] - cmc - cm_sh[e]) * 0.0625f;
            lg[e] = l;
            mx = fmaxf(mx, l);
        }
        float s = 0.f;
        for (int e = 0; e < 32; ++e) { float ex = __expf(lg[e] - mx); lg[e] = ex; s += ex; }
        float inv = 1.f / s;
        for (int e = 0; e < 32; ++e) dp_f[c * 33 + e] = lg[e] * inv;
    }
    __syncthreads();
    if (tid < 32) {
        int e = tid;
        float a2 = 0.f;
        for (int c = 0; c < 32; ++c) a2 += gate_sh[c] * dp_f[c * 33 + e];
        w_sh[e] = a2;
    }
    __syncthreads();

    float accv = 0.f;
    int d = tid;
    for (int e = 0; e < 32; ++e)
        accv += w_sh[e] * bf2f(x_bf[e * 256 + (d ^ ((e & 7) << 3))]);
    vv[(size_t)bag * 256 + d] = accv;
}

// ---------------------------------------------------------------------------
// x1_mfma: X1bf[t][b][d][gate] = bf16( vv @ Wih1^T + lstm_b )
// ---------------------------------------------------------------------------
__global__ void __launch_bounds__(256) x1_mfma(const float* __restrict__ vv,
                                               const unsigned short* __restrict__ W1h,
                                               const unsigned short* __restrict__ W1l,
                                               const float* __restrict__ lstm_b,
                                               unsigned short* __restrict__ X1bf) {
    __shared__ __align__(16) unsigned short xs[32 * 256];
    int blk = blockIdx.x;
    int rb = blk >> 3, gb = blk & 7;
    int tid = threadIdx.x;
    for (int it = 0; it < 8; ++it) {
        int idx = it * 256 + tid;
        int row = idx >> 6, f4 = idx & 63;
        float4 v = *reinterpret_cast<const float4*>(vv + (size_t)(rb * 32 + row) * 256 + f4 * 4);
        ushort4 w;
        w.x = f2bf(v.x); w.y = f2bf(v.y); w.z = f2bf(v.z); w.w = f2bf(v.w);
        *reinterpret_cast<ushort4*>(&xs[row * 256 + ((f4 * 4) ^ ((row & 7) << 3))]) = w;
    }
    __syncthreads();
    int wv = tid >> 6, lane = tid & 63, cl = lane & 15, kh = lane >> 4;
    f32x4 acc[2][2];
    for (int n = 0; n < 2; ++n) {
        int nt = gb * 8 + wv * 2 + n;
        float bz = lstm_b[nt * 16 + cl];
        acc[n][0] = (f32x4){bz, bz, bz, bz};
        acc[n][1] = (f32x4){bz, bz, bz, bz};
    }
    #pragma unroll
    for (int kb = 0; kb < 8; ++kb) {
        int k = kb * 32 + kh * 8;
        bf16x8 a0 = *reinterpret_cast<const bf16x8*>(&xs[cl * 256 + (k ^ ((cl & 7) << 3))]);
        bf16x8 a1 = *reinterpret_cast<const bf16x8*>(&xs[(16 + cl) * 256 + (k ^ (((16 + cl) & 7) << 3))]);
        for (int n = 0; n < 2; ++n) {
            int nt = gb * 8 + wv * 2 + n;
            size_t o = ((size_t)(nt * 8 + kb) * 64 + lane) * 8;
            bf16x8 bh = *reinterpret_cast<const bf16x8*>(W1h + o);
            bf16x8 bl = *reinterpret_cast<const bf16x8*>(W1l + o);
            acc[n][0] = __builtin_amdgcn_mfma_f32_16x16x32_bf16(a0, bh, acc[n][0], 0, 0, 0);
            acc[n][0] = __builtin_amdgcn_mfma_f32_16x16x32_bf16(a0, bl, acc[n][0], 0, 0, 0);
            acc[n][1] = __builtin_amdgcn_mfma_f32_16x16x32_bf16(a1, bh, acc[n][1], 0, 0, 0);
            acc[n][1] = __builtin_amdgcn_mfma_f32_16x16x32_bf16(a1, bl, acc[n][1], 0, 0, 0);
        }
    }
    for (int n = 0; n < 2; ++n) {
        int nt = gb * 8 + wv * 2 + n;
        int g = nt * 16 + cl;
        int dX = g & 255, gt = g >> 8;
        for (int mt = 0; mt < 2; ++mt)
            for (int r = 0; r < 4; ++r) {
                int row = rb * 32 + mt * 16 + kh * 4 + r;
                int b = row >> 6, t = row & 63;
                X1bf[((size_t)t * 32 + b) * 1024 + dX * 4 + gt] = f2bf(acc[n][mt][r]);
            }
    }
}

// ---------------------------------------------------------------------------
// lstm_persist: flag-first discovery + payload-validated data, ONE hop/step.
// h stored as h' = h+3 (band 0x40). Producer: data stores then flag, NO drain.
// Consumer: poll flags -> load data -> band check -> (rare) retry.
// A (wgs 0..15): all-gates-per-wave, tr4, no LDS. flags[p*192 + slot(0..63)].
// B (wgs 16..31..47): mat-split all-gates d-slice-4 waves, zbuf combine.
//   flags[s*192 + 64 + slot2(0..127)].
// Weights hi-only bf16; shift folded via corr = 3*rowsum(W_hi).
// ---------------------------------------------------------------------------
__global__ void __launch_bounds__(256, 1) lstm_persist(
    const unsigned short* __restrict__ Wpk_hi,
    const unsigned short* __restrict__ X1bf, const float* __restrict__ hs_b,
    const float* __restrict__ corrA, const float* __restrict__ corrB,
    unsigned short* h1, unsigned short* h2, int* flags) {
    int wg = blockIdx.x, tid = threadIdx.x;
    int wv = tid >> 6, lane = tid & 63;
    int c = lane & 15, grp = lane >> 4;
    int q = c & 3, dloc = c >> 2;
    bool isA = wg < 16;

    if (isA) {
        int slot = wg * 4 + wv;
        int d = slot * 4 + dloc;
        int b0 = grp * 4 + q;
        bf16x8 wh[8];
        #pragma unroll
        for (int kb = 0; kb < 8; ++kb)
            wh[kb] = *reinterpret_cast<const bf16x8*>(
                Wpk_hi + ((size_t)(slot * 8 + kb) * 64 + lane) * 8);
        float corrv = corrA[slot * 16 + c];
        float cst0 = 0.f, cst1 = 0.f;
        for (int p = 0; p < 64; ++p) {
            ushort4 x1v0 = *reinterpret_cast<const ushort4*>(
                X1bf + (((size_t)p * 32 + b0) * 256 + d) * 4);
            ushort4 x1v1 = *reinterpret_cast<const ushort4*>(
                X1bf + (((size_t)p * 32 + b0 + 16) * 256 + d) * 4);
            f32x4 acc0 = (f32x4){0.f, 0.f, 0.f, 0.f};
            f32x4 acc1 = acc0;
            if (p > 0) {
                const int* f = flags + (p - 1) * 192;
                while (1) {
                    int v = __hip_atomic_load(f + lane, __ATOMIC_RELAXED, __HIP_MEMORY_SCOPE_AGENT);
                    if (__all(v != 0)) break;
                    __builtin_amdgcn_s_sleep(1);
                }
                __builtin_amdgcn_sched_barrier(0);
                acc0 = (f32x4){-corrv, -corrv, -corrv, -corrv};
                acc1 = acc0;
                const unsigned short* hB = h1 + (size_t)(p - 1) * 8192;
                bf16x8 a0[8], a1[8];
                while (true) {
                    #pragma unroll
                    for (int kb = 0; kb < 8; ++kb) {
                        a0[kb] = ldg_sc(hB + c * 256 + kb * 32 + grp * 8);
                        a1[kb] = ldg_sc(hB + (16 + c) * 256 + kb * 32 + grp * 8);
                    }
                    asm volatile("s_waitcnt vmcnt(0)" ::: "memory");
                    __builtin_amdgcn_sched_barrier(0);
                    unsigned int bad = 0;
                    #pragma unroll
                    for (int kb = 0; kb < 8; ++kb)
                        bad |= frag_bad(a0[kb]) | frag_bad(a1[kb]);
                    if (__all(bad == 0)) break;
                    __builtin_amdgcn_s_sleep(1);
                }
                __builtin_amdgcn_sched_barrier(0);
                #pragma unroll
                for (int kb = 0; kb < 8; ++kb) {
                    acc0 = __builtin_amdgcn_mfma_f32_16x16x32_bf16(a0[kb], wh[kb], acc0, 0, 0, 0);
                    acc1 = __builtin_amdgcn_mfma_f32_16x16x32_bf16(a1[kb], wh[kb], acc1, 0, 0, 0);
                }
            }
            float za[4] = {acc0[0], acc0[1], acc0[2], acc0[3]};
            float zb[4] = {acc1[0], acc1[1], acc1[2], acc1[3]};
            tr4(za, q);
            tr4(zb, q);
            float zi = za[0] + bf2f(x1v0.x);
            float zf = za[1] + bf2f(x1v0.y);
            float zg = za[2] + bf2f(x1v0.z);
            float zo = za[3] + bf2f(x1v0.w);
            float cn0 = sigm_f(zf) * cst0 + sigm_f(zi) * tanh_f(zg);
            float hn0 = sigm_f(zo) * tanh_f(cn0);
            cst0 = cn0;
            zi = zb[0] + bf2f(x1v1.x);
            zf = zb[1] + bf2f(x1v1.y);
            zg = zb[2] + bf2f(x1v1.z);
            zo = zb[3] + bf2f(x1v1.w);
            float cn1 = sigm_f(zf) * cst1 + sigm_f(zi) * tanh_f(zg);
            float hn1 = sigm_f(zo) * tanh_f(cn1);
            cst1 = cn1;
            unsigned int pk0 = f2bf(hn0 + 3.f), pk1 = f2bf(hn1 + 3.f);
            unsigned int pr0 = (unsigned int)__shfl_xor((int)pk0, 4);
            unsigned int pr1 = (unsigned int)__shfl_xor((int)pk1, 4);
            if ((c & 4) == 0) {
                __hip_atomic_store((unsigned int*)h1 + ((((size_t)p * 32 + b0) * 256 + d) >> 1),
                                   pk0 | (pr0 << 16), __ATOMIC_RELAXED, __HIP_MEMORY_SCOPE_AGENT);
                __hip_atomic_store((unsigned int*)h1 + ((((size_t)p * 32 + b0 + 16) * 256 + d) >> 1),
                                   pk1 | (pr1 << 16), __ATOMIC_RELAXED, __HIP_MEMORY_SCOPE_AGENT);
            }
            if (lane == 0)   // no drain: flag follows data in issue order
                __hip_atomic_store(flags + p * 192 + slot, 1,
                                   __ATOMIC_RELAXED, __HIP_MEMORY_SCOPE_AGENT);
        }
    } else {
        __shared__ float zbuf[4][16][33];
        int slot2 = (wg - 16) * 4 + wv;         // 0..127
        int mat = slot2 & 1;                    // 0: Wih2*h1[s], 1: Whh2*h2[s-1]
        bf16x8 wh[8];
        #pragma unroll
        for (int kb = 0; kb < 8; ++kb)
            wh[kb] = *reinterpret_cast<const bf16x8*>(
                Wpk_hi + ((size_t)(512 + slot2 * 8 + kb) * 64 + lane) * 8);
        float corrv = corrB[slot2 * 16 + c];
        int bR = tid & 31;
        int idx = tid >> 5;
        int sl_loc = idx >> 2, dlocR = idx & 3;
        int dG = ((wg - 16) * 2 + sl_loc) * 4 + dlocR;
        float bias[4];
        #pragma unroll
        for (int g = 0; g < 4; ++g) bias[g] = hs_b[g * 256 + dG];
        float cst = 0.f;
        for (int s = 0; s < 64; ++s) {
            {
                const int* fA = flags + s * 192;
                const int* fB = flags + (s - 1) * 192 + 64;
                while (1) {
                    int va = __hip_atomic_load(fA + lane, __ATOMIC_RELAXED, __HIP_MEMORY_SCOPE_AGENT);
                    int ok = (va != 0);
                    if (s > 0) {
                        int v1 = __hip_atomic_load(fB + lane, __ATOMIC_RELAXED, __HIP_MEMORY_SCOPE_AGENT);
                        int v2 = __hip_atomic_load(fB + 64 + lane, __ATOMIC_RELAXED, __HIP_MEMORY_SCOPE_AGENT);
                        ok = ok && (v1 != 0) && (v2 != 0);
                    }
                    if (__all(ok)) break;
                    __builtin_amdgcn_s_sleep(1);
                }
                __builtin_amdgcn_sched_barrier(0);
            }
            f32x4 acc0 = (f32x4){0.f, 0.f, 0.f, 0.f};
            f32x4 acc1 = acc0;
            bool active = (mat == 0) || (s > 0);
            if (active) {
                acc0 = (f32x4){-corrv, -corrv, -corrv, -corrv};
                acc1 = acc0;
                const unsigned short* hB =
                    (mat == 0) ? (h1 + (size_t)s * 8192) : (h2 + (size_t)(s - 1) * 8192);
                bf16x8 a0[8], a1[8];
                while (true) {
                    #pragma unroll
                    for (int kb = 0; kb < 8; ++kb) {
                        a0[kb] = ldg_sc(hB + c * 256 + kb * 32 + grp * 8);
                        a1[kb] = ldg_sc(hB + (16 + c) * 256 + kb * 32 + grp * 8);
                    }
                    asm volatile("s_waitcnt vmcnt(0)" ::: "memory");
                    __builtin_amdgcn_sched_barrier(0);
                    unsigned int bad = 0;
                    #pragma unroll
                    for (int kb = 0; kb < 8; ++kb)
                        bad |= frag_bad(a0[kb]) | frag_bad(a1[kb]);
                    if (__all(bad == 0)) break;
                    __builtin_amdgcn_s_sleep(1);
                }
                __builtin_amdgcn_sched_barrier(0);
                #pragma unroll
                for (int kb = 0; kb < 8; ++kb) {
                    acc0 = __builtin_amdgcn_mfma_f32_16x16x32_bf16(a0[kb], wh[kb], acc0, 0, 0, 0);
                    acc1 = __builtin_amdgcn_mfma_f32_16x16x32_bf16(a1[kb], wh[kb], acc1, 0, 0, 0);
                }
            }
            __syncthreads();
            #pragma unroll
            for (int r = 0; r < 4; ++r) {
                zbuf[wv][c][grp * 4 + r] = acc0[r];
                zbuf[wv][c][16 + grp * 4 + r] = acc1[r];
            }
            __syncthreads();
            float z[4];
            #pragma unroll
            for (int g = 0; g < 4; ++g)
                z[g] = zbuf[2 * sl_loc][dlocR * 4 + g][bR] +
                       zbuf[2 * sl_loc + 1][dlocR * 4 + g][bR] + bias[g];
            float cn = sigm_f(z[1]) * cst + sigm_f(z[0]) * tanh_f(z[2]);
            float hn = sigm_f(z[3]) * tanh_f(cn);
            cst = cn;
            unsigned int pk = f2bf(hn + 3.f);
            unsigned int pr = (unsigned int)__shfl_xor((int)pk, 32);
            if ((idx & 1) == 0)
                __hip_atomic_store((unsigned int*)h2 + ((((size_t)s * 32 + bR) * 256 + dG) >> 1),
                                   pk | (pr << 16), __ATOMIC_RELAXED, __HIP_MEMORY_SCOPE_AGENT);
            if (lane == 0)
                __hip_atomic_store(flags + s * 192 + 64 + slot2, 1,
                                   __ATOMIC_RELAXED, __HIP_MEMORY_SCOPE_AGENT);
        }
    }
}

// ---------------------------------------------------------------------------
// tail_k: per batch, only v* = lengths[b]-1 matters. Transposed weights
// (coalesced) + 4-acc ILP. h decode: -3.
// ---------------------------------------------------------------------------
__global__ void __launch_bounds__(256) tail_k(
    const int* __restrict__ lengths,
    const unsigned short* __restrict__ h1, const unsigned short* __restrict__ h2,
    const float* __restrict__ whkT, const float* __restrict__ whk_b,
    const float* __restrict__ w1T, const float* __restrict__ w1_b,
    const float* __restrict__ w2_W, const float* __restrict__ w2_b,
    const float* __restrict__ fuseT, const float* __restrict__ fuse_b,
    const float* __restrict__ lab_W, const float* __restrict__ lab_b,
    const float* __restrict__ Wdiff, const float* __restrict__ alpha,
    const float* __restrict__ noise, float* __restrict__ out) {
    __shared__ float ek[256], tv[256], hs[256], whp[256], a1s[64];
    __shared__ float noisy_s[256], fin[512], fused_s[256], attn_s[2];
    int b = blockIdx.x, tid = threadIdx.x;
    int vstar = lengths[b] - 1;
    {
        ek[tid] = bf2f(h1[(size_t)b * 256 + tid]) - 3.f;
        tv[tid] = bf2f(h1[((size_t)vstar * 32 + b) * 256 + tid]) - 3.f;
        if (vstar > 0)
            hs[tid] = bf2f(h2[((size_t)(vstar - 1) * 32 + b) * 256 + tid]) - 3.f;
    }
    __syncthreads();

    float aligned;
    if (vstar > 0) {
        float s0 = 0.f, s1 = 0.f, s2 = 0.f, s3 = 0.f;
        for (int k = 0; k < 256; k += 4) {
            s0 += whkT[(k + 0) * 256 + tid] * hs[k + 0];
            s1 += whkT[(k + 1) * 256 + tid] * hs[k + 1];
            s2 += whkT[(k + 2) * 256 + tid] * hs[k + 2];
            s3 += whkT[(k + 3) * 256 + tid] * hs[k + 3];
        }
        whp[tid] = whk_b[tid] + s0 + s1 + s2 + s3;
        __syncthreads();
        if (tid < 64) {
            float a0 = 0.f, a1 = 0.f, a2 = 0.f, a3 = 0.f;
            for (int k = 0; k < 256; k += 4) {
                a0 += w1T[(k + 0) * 64 + tid] * ek[k + 0];
                a1 += w1T[(k + 1) * 64 + tid] * ek[k + 1];
                a2 += w1T[(k + 2) * 64 + tid] * ek[k + 2];
                a3 += w1T[(k + 3) * 64 + tid] * ek[k + 3];
            }
            for (int k = 0; k < 256; k += 4) {
                a0 += w1T[(256 + k + 0) * 64 + tid] * whp[k + 0];
                a1 += w1T[(256 + k + 1) * 64 + tid] * whp[k + 1];
                a2 += w1T[(256 + k + 2) * 64 + tid] * whp[k + 2];
                a3 += w1T[(256 + k + 3) * 64 + tid] * whp[k + 3];
            }
            a1s[tid] = tanhf(w1_b[tid] + a0 + a1 + a2 + a3);
        }
        __syncthreads();
        if (tid < 2) {
            float a3 = w2_b[tid];
            const float* wr2 = w2_W + tid * 64;
            for (int k = 0; k < 64; ++k) a3 += wr2[k] * a1s[k];
            attn_s[tid] = a3;
        }
        __syncthreads();
        float m = fmaxf(attn_s[0], attn_s[1]);
        float e0 = __expf(attn_s[0] - m), e1 = __expf(attn_s[1] - m);
        float inv = 1.f / (e0 + e1);
        aligned = ek[tid] * (e0 * inv) + whp[tid] * (e1 * inv);
    } else {
        aligned = ek[tid];
    }

    float al = alpha[b];
    float sa = sqrtf(al), sb = sqrtf(1.f - al);
    float nz = noise[((size_t)b * 64 + vstar) * 256 + tid];
    noisy_s[tid] = aligned * sa + nz * sb;
    __syncthreads();
    {
        float p0 = 0.f, p1 = 0.f, p2 = 0.f, p3 = 0.f;
        for (int k = 0; k < 256; k += 4) {
            p0 += noisy_s[k + 0] * Wdiff[(size_t)(k + 0) * 256 + tid];
            p1 += noisy_s[k + 1] * Wdiff[(size_t)(k + 1) * 256 + tid];
            p2 += noisy_s[k + 2] * Wdiff[(size_t)(k + 2) * 256 + tid];
            p3 += noisy_s[k + 3] * Wdiff[(size_t)(k + 3) * 256 + tid];
        }
        float gen = aligned + nz - (p0 + p1 + p2 + p3);
        fin[tid] = tv[tid];
        fin[256 + tid] = gen;
    }
    __syncthreads();
    {
        float f0 = 0.f, f1 = 0.f, f2 = 0.f, f3 = 0.f;
        for (int k = 0; k < 512; k += 4) {
            f0 += fuseT[(k + 0) * 256 + tid] * fin[k + 0];
            f1 += fuseT[(k + 1) * 256 + tid] * fin[k + 1];
            f2 += fuseT[(k + 2) * 256 + tid] * fin[k + 2];
            f3 += fuseT[(k + 3) * 256 + tid] * fin[k + 3];
        }
        fused_s[tid] = fuse_b[tid] + f0 + f1 + f2 + f3;
    }
    __syncthreads();
    if (tid < 2) {
        float o = lab_b[tid];
        const float* lw = lab_W + tid * 256;
        for (int k = 0; k < 256; ++k) o += lw[k] * fused_s[k];
        out[b * 2 + tid] = o;
    }
}

// ---------------------------------------------------------------------------
extern "C" void kernel_launch(void* const* d_in, const int* in_sizes, int n_in,
                              void* d_out, int out_size, void* d_ws, size_t ws_size,
                              hipStream_t stream) {
    const int*   seqs    = (const int*)  d_in[0];
    const int*   lengths = (const int*)  d_in[2];
    const float* tstep   = (const float*)d_in[3];
    const float* cmask   = (const float*)d_in[4];
    const float* emb     = (const float*)d_in[5];
    const float* WQ1     = (const float*)d_in[6];
    const float* WK1     = (const float*)d_in[7];
    const float* decay   = (const float*)d_in[8];
    const float* initial = (const float*)d_in[9];
    const float* Wih1    = (const float*)d_in[10];
    const float* Whh1    = (const float*)d_in[11];
    const float* lstm_b  = (const float*)d_in[12];
    const float* Wih2    = (const float*)d_in[13];
    const float* Whh2    = (const float*)d_in[14];
    const float* hs_b    = (const float*)d_in[15];
    const float* whk_W   = (const float*)d_in[16];
    const float* whk_b   = (const float*)d_in[17];
    const float* w1_W    = (const float*)d_in[18];
    const float* w1_b    = (const float*)d_in[19];
    const float* w2_W    = (const float*)d_in[20];
    const float* w2_b    = (const float*)d_in[21];
    const float* fuse_W  = (const float*)d_in[22];
    const float* fuse_b  = (const float*)d_in[23];
    const float* lab_W   = (const float*)d_in[24];
    const float* lab_b   = (const float*)d_in[25];
    const float* betas   = (const float*)d_in[26];
    const float* Wdiff   = (const float*)d_in[27];
    const int*   dift    = (const int*)  d_in[28];
    const float* noise   = (const float*)d_in[29];
    float* out = (float*)d_out;

    float* ws = (float*)d_ws;
    size_t off = 0;
    auto alloc = [&](size_t nfloats) { size_t r = off; off += (nfloats + 63) & ~(size_t)63; return r; };
    unsigned short* M_pk   = (unsigned short*)(ws + alloc(32768));
    float*          alpha  = ws + alloc(64);
    float*          corrA  = ws + alloc(1024);
    float*          corrB  = ws + alloc(2048);
    int*            flags  = (int*)(ws + alloc(12288));
    float*          vv     = ws + alloc(524288);
    unsigned short* X1bf   = (unsigned short*)(ws + alloc(1048576));  // 64*32*1024 u16
    unsigned short* h1     = (unsigned short*)(ws + alloc(262144));   // 64*32*256 u16
    unsigned short* h2     = (unsigned short*)(ws + alloc(262144));
    unsigned short* Wpk_hi = (unsigned short*)(ws + alloc(393216));   // 1536 chunks * 512 u16
    unsigned short* W1h    = (unsigned short*)(ws + alloc(131072));
    unsigned short* W1l    = (unsigned short*)(ws + alloc(131072));
    float*          whkT   = ws + alloc(65536);
    float*          fuseT  = ws + alloc(131072);
    float*          w1T    = ws + alloc(32768);

    pack_all<<<1077, 256, 0, stream>>>(Whh1, Wih2, Whh2, Wih1, WQ1, WK1, betas, dift,
                                       whk_W, fuse_W, w1_W,
                                       Wpk_hi, W1h, W1l, M_pk, corrA, corrB, alpha,
                                       flags, (unsigned int*)h1, (unsigned int*)h2,
                                       whkT, fuseT, w1T);
    attn_bags<<<2048, 256, 0, stream>>>(seqs, tstep, cmask, emb, decay, initial, M_pk, vv);
    x1_mfma<<<512, 256, 0, stream>>>(vv, W1h, W1l, lstm_b, X1bf);
    lstm_persist<<<48, 256, 0, stream>>>(Wpk_hi, X1bf, hs_b, corrA, corrB, h1, h2, flags);
    tail_k<<<32, 256, 0, stream>>>(lengths, h1, h2, whkT, whk_b,
                                   w1T, w1_b, w2_W, w2_b, fuseT, fuse_b,
                                   lab_W, lab_b, Wdiff, alpha, noise, out);
}

// Round 7
// 339.963 us; speedup vs baseline: 1.9457x; 1.6943x over previous
//
#include <hip/hip_runtime.h>
#include <hip/hip_bf16.h>
#include <cmath>

typedef __attribute__((ext_vector_type(8))) short bf16x8;
typedef __attribute__((ext_vector_type(4))) float f32x4;
typedef __attribute__((ext_vector_type(4))) int i32x4;
typedef __attribute__((ext_vector_type(2))) unsigned int u32x2;

__device__ __forceinline__ float bf2f(unsigned short u) {
    unsigned int x = ((unsigned int)u) << 16;
    return __builtin_bit_cast(float, x);
}
__device__ __forceinline__ unsigned short f2bf(float f) {
    unsigned int x = __builtin_bit_cast(unsigned int, f);
    unsigned int lsb = (x >> 16) & 1u;
    x += 0x7fffu + lsb;
    return (unsigned short)(x >> 16);
}
__device__ __forceinline__ float sigm(float z) {
    return 1.f / (1.f + __expf(-z));
}
__device__ __forceinline__ float rcpf(float x) { return __builtin_amdgcn_rcpf(x); }
__device__ __forceinline__ float sigm_f(float z) { return rcpf(1.f + __expf(-z)); }
__device__ __forceinline__ float tanh_f(float z) { return 1.f - 2.f * rcpf(1.f + __expf(2.f * z)); }

// sc1 (agent-coherent, IF$) memory helpers
__device__ __forceinline__ long ldg_sc8l(const void* p) {
    long r;
    asm volatile("global_load_dwordx2 %0, %1, off sc1" : "=v"(r) : "v"(p) : "memory");
    return r;
}
__device__ __forceinline__ u32x2 ldg_sc_u2(const void* p) {
    u32x2 r;
    asm volatile("global_load_dwordx2 %0, %1, off sc1" : "=v"(r) : "v"(p) : "memory");
    return r;
}
__device__ __forceinline__ void stg_sc_u2(void* p, u32x2 v) {
    asm volatile("global_store_dwordx2 %0, %1, off sc1" :: "v"(p), "v"(v) : "memory");
}
__device__ __forceinline__ void stg_sc_b(void* p, int v) {
    asm volatile("global_store_byte %0, %1, off sc1" :: "v"(p), "v"(v) : "memory");
}

// ---------------------------------------------------------------------------
// pack_all — all prep, block-range dispatched:
// [0,384)    i8 quantize Whh1/Wih2/Whh2 -> Wq frags + cs row scales
// [384,512)  pack_w1 (Wih1 bf16-hi fragments)
// 512        alpha cumprod
// 513        zero flags (2048 ints)
// [514,578)  whkT   [578,706) fuseT   [706,738) w1T
// [738,802)  prep_M (M = WQ1^T@WK1, MFMA B-frag order)
// ---------------------------------------------------------------------------
__global__ void __launch_bounds__(256) pack_all(
    const float* __restrict__ Whh1, const float* __restrict__ Wih2,
    const float* __restrict__ Whh2, const float* __restrict__ Wih1,
    const float* __restrict__ WQ1, const float* __restrict__ WK1,
    const float* __restrict__ betas, const int* __restrict__ dift,
    const float* __restrict__ whk_W, const float* __restrict__ fuse_W,
    const float* __restrict__ w1_W,
    long* __restrict__ Wq, float* __restrict__ cs,
    unsigned short* __restrict__ W1h, unsigned short* __restrict__ M_pk,
    float* __restrict__ alpha, int* __restrict__ flags,
    float* __restrict__ whkT, float* __restrict__ fuseT,
    float* __restrict__ w1T) {
    int blk = blockIdx.x, tid = threadIdx.x;
    if (blk < 384) {
        int R = blk * 8 + (tid >> 5);       // row 0..3071
        int mat = R >> 10;
        int n = R & 1023;
        int t32 = tid & 31;
        const float* src = (mat == 0) ? Whh1 : (mat == 1 ? Wih2 : Whh2);
        const float* rp = src + (size_t)n * 256 + t32 * 8;
        float v[8];
        float mx = 0.f;
        for (int j = 0; j < 8; ++j) { v[j] = rp[j]; mx = fmaxf(mx, fabsf(v[j])); }
        for (int m = 1; m <= 16; m <<= 1) mx = fmaxf(mx, __shfl_xor(mx, m));
        float inv = mx > 0.f ? 127.f / mx : 0.f;
        unsigned int lo = 0, hi = 0;
        for (int j = 0; j < 4; ++j) {
            int iv = __float2int_rn(v[j] * inv);
            lo |= ((unsigned int)(unsigned char)(signed char)iv) << (8 * j);
            int iv2 = __float2int_rn(v[4 + j] * inv);
            hi |= ((unsigned int)(unsigned char)(signed char)iv2) << (8 * j);
        }
        int g = n >> 8, rem = n & 255;
        int w8 = rem >> 5, dt = (rem >> 4) & 1, cc = rem & 15;
        int t8 = g * 2 + dt;
        int kb = t32 >> 2, q = t32 & 3;
        unsigned int* dst = (unsigned int*)Wq +
            ((size_t)((mat * 512 + w8 * 64 + t8 * 8 + kb) * 64) + q * 16 + cc) * 2;
        dst[0] = lo;
        dst[1] = hi;
        if (t32 == 0) cs[mat * 1024 + n] = mx / 16129.f;   // (mx/127)/127
    } else if (blk < 512) {
        int cch = (blk - 384) * 256 + tid;
        int nt = cch >> 9;
        int r = cch & 511;
        int kb = r >> 6;
        int lane = r & 63;
        int grow = nt * 16 + (lane & 15);
        int k0 = kb * 32 + (lane >> 4) * 8;
        const float* sp = Wih1 + (size_t)grow * 256 + k0;
        bf16x8 hi;
        for (int j = 0; j < 8; ++j) hi[j] = (short)f2bf(sp[j]);
        *reinterpret_cast<bf16x8*>(W1h + (size_t)cch * 8) = hi;
    } else if (blk == 512) {
        if (tid < 32) {
            int tb = dift[tid];
            float p = 1.f;
            for (int i = 0; i <= tb; ++i) p *= (1.f - betas[i]);
            alpha[tid] = p;
        }
    } else if (blk == 513) {
        for (int i = tid; i < 2048; i += 256) flags[i] = 0;
    } else if (blk < 578) {
        int gid = (blk - 514) * 256 + tid;
        for (int i = 0; i < 4; ++i) {
            int e = gid + i * 16384;
            int k = e >> 8, dd = e & 255;
            whkT[e] = whk_W[(size_t)dd * 256 + k];
        }
    } else if (blk < 706) {
        int gid = (blk - 578) * 256 + tid;
        for (int i = 0; i < 4; ++i) {
            int e = gid + i * 32768;
            int k = e >> 8, dd = e & 255;
            fuseT[e] = fuse_W[(size_t)dd * 512 + k];
        }
    } else if (blk < 738) {
        int gid = (blk - 706) * 256 + tid;
        for (int i = 0; i < 4; ++i) {
            int e = gid + i * 8192;
            int k = e >> 6, j = e & 63;
            w1T[e] = w1_W[(size_t)j * 512 + k];
        }
    } else {
        __shared__ unsigned short As[256][32];
        __shared__ unsigned short Bs[256][32];
        int bx = blk - 738;
        int e0 = (bx >> 3) << 5;
        int f0 = (bx & 7) << 5;
        int col = tid & 31, rr = tid >> 5;
        for (int rep = 0; rep < 32; ++rep) {
            int d = rep * 8 + rr;
            As[d][col] = f2bf(WQ1[d * 256 + e0 + col]);
            Bs[d][col] = f2bf(WK1[d * 256 + f0 + col]);
        }
        __syncthreads();
        int el = tid & 31;
        int fl0 = tid >> 5;
        for (int i = 0; i < 4; ++i) {
            int fl = fl0 + 8 * i;
            float acc = 0.f;
            for (int d = 0; d < 256; ++d)
                acc += bf2f(As[d][el]) * bf2f(Bs[d][fl]);
            int e = e0 + el, f = f0 + fl;
            int kb = e >> 5, r = (e >> 3) & 3, j = e & 7;
            int nb = f >> 4;
            int lane = (r << 4) | (f & 15);
            M_pk[(((nb * 8 + kb) * 64) + lane) * 8 + j] = f2bf(acc);
        }
    }
}

// ---------------------------------------------------------------------------
// attn_bags (unchanged, verified)
// ---------------------------------------------------------------------------
__global__ void __launch_bounds__(256) attn_bags(
    const int* __restrict__ seqs, const float* __restrict__ tstep,
    const float* __restrict__ cmask, const float* __restrict__ emb,
    const float* __restrict__ decay, const float* __restrict__ initial,
    const unsigned short* __restrict__ M_pk, float* __restrict__ vv) {
    __shared__ __align__(16) unsigned short x_bf[32 * 256];
    __shared__ __align__(16) unsigned short t1_bf[32 * 256];
    __shared__ float dp_f[32 * 33];
    __shared__ float gate_sh[32];
    __shared__ float cm_sh[32];
    __shared__ int tok_sh[32];
    __shared__ float w_sh[32];

    int bag = blockIdx.x;
    int tid = threadIdx.x;

    if (tid < 32) {
        int tok = seqs[bag * 32 + tid];
        tok_sh[tid] = tok;
        float cm = cmask[bag * 32 + tid];
        cm_sh[tid] = cm;
        float tt = tstep[bag];
        float g = sigm(decay[tok] * tt + initial[tok]);
        g *= (cm - 1e20f) / (-1e20f);
        gate_sh[tid] = g;
    }
    __syncthreads();

    for (int it = 0; it < 8; ++it) {
        int fidx = it * 256 + tid;
        int c = fidx >> 6;
        int f4 = fidx & 63;
        const float4* src = reinterpret_cast<const float4*>(emb + (size_t)tok_sh[c] * 256) + f4;
        float4 vx = *src;
        int colx = f4 * 4;
        int eidx = c * 256 + (colx ^ ((c & 7) << 3));
        ushort4 w;
        w.x = f2bf(vx.x); w.y = f2bf(vx.y); w.z = f2bf(vx.z); w.w = f2bf(vx.w);
        *reinterpret_cast<ushort4*>(&x_bf[eidx]) = w;
    }
    __syncthreads();

    int wv = tid >> 6;
    int lane = tid & 63;
    int lr = lane & 15;
    int lk = lane >> 4;

    f32x4 acc[2][4];
    for (int a = 0; a < 2; ++a)
        for (int n = 0; n < 4; ++n) acc[a][n] = (f32x4){0.f, 0.f, 0.f, 0.f};
    for (int kb = 0; kb < 8; ++kb) {
        bf16x8 afr[2];
        for (int mb = 0; mb < 2; ++mb) {
            int row = mb * 16 + lr;
            int colx = kb * 32 + lk * 8;
            afr[mb] = *reinterpret_cast<const bf16x8*>(&x_bf[row * 256 + (colx ^ ((row & 7) << 3))]);
        }
        for (int nbi = 0; nbi < 4; ++nbi) {
            int nb = wv * 4 + nbi;
            bf16x8 bfr = *reinterpret_cast<const bf16x8*>(M_pk + (((nb * 8 + kb) * 64) + lane) * 8);
            acc[0][nbi] = __builtin_amdgcn_mfma_f32_16x16x32_bf16(afr[0], bfr, acc[0][nbi], 0, 0, 0);
            acc[1][nbi] = __builtin_amdgcn_mfma_f32_16x16x32_bf16(afr[1], bfr, acc[1][nbi], 0, 0, 0);
        }
    }
    for (int mb = 0; mb < 2; ++mb)
        for (int nbi = 0; nbi < 4; ++nbi)
            for (int r = 0; r < 4; ++r) {
                int row = mb * 16 + lk * 4 + r;
                int colx = wv * 64 + nbi * 16 + lr;
                t1_bf[row * 256 + (colx ^ ((row & 7) << 3))] = f2bf(acc[mb][nbi][r]);
            }
    __syncthreads();

    {
        int mb = wv >> 1, nb2 = wv & 1;
        f32x4 dacc = (f32x4){0.f, 0.f, 0.f, 0.f};
        for (int kb = 0; kb < 8; ++kb) {
            int cola = kb * 32 + lk * 8;
            int rowa = mb * 16 + lr;
            bf16x8 afr = *reinterpret_cast<const bf16x8*>(&t1_bf[rowa * 256 + (cola ^ ((rowa & 7) << 3))]);
            int rowb = nb2 * 16 + lr;
            bf16x8 bfr = *reinterpret_cast<const bf16x8*>(&x_bf[rowb * 256 + (cola ^ ((rowb & 7) << 3))]);
            dacc = __builtin_amdgcn_mfma_f32_16x16x32_bf16(afr, bfr, dacc, 0, 0, 0);
        }
        for (int r = 0; r < 4; ++r) {
            int c = mb * 16 + lk * 4 + r;
            int e = nb2 * 16 + lr;
            dp_f[c * 33 + e] = dacc[r];
        }
    }
    __syncthreads();

    if (tid < 32) {
        int c = tid;
        float cmc = cm_sh[c];
        float lg[32];
        float mx = -1e30f;
        for (int e = 0; e < 32; ++e) {
            float l = (dp_f[c * 33 + e] - cmc - cm_sh[e]) * 0.0625f;
            lg[e] = l;
            mx = fmaxf(mx, l);
        }
        float s = 0.f;
        for (int e = 0; e < 32; ++e) { float ex = __expf(lg[e] - mx); lg[e] = ex; s += ex; }
        float inv = 1.f / s;
        for (int e = 0; e < 32; ++e) dp_f[c * 33 + e] = lg[e] * inv;
    }
    __syncthreads();
    if (tid < 32) {
        int e = tid;
        float a2 = 0.f;
        for (int c = 0; c < 32; ++c) a2 += gate_sh[c] * dp_f[c * 33 + e];
        w_sh[e] = a2;
    }
    __syncthreads();

    float accv = 0.f;
    int d = tid;
    for (int e = 0; e < 32; ++e)
        accv += w_sh[e] * bf2f(x_bf[e * 256 + (d ^ ((e & 7) << 3))]);
    vv[(size_t)bag * 256 + d] = accv;
}

// ---------------------------------------------------------------------------
// x1_mfma: X1bf[t][b][d][gate] = bf16( vv @ Wih1^T + lstm_b ), hi-only.
// ---------------------------------------------------------------------------
__global__ void __launch_bounds__(256) x1_mfma(const float* __restrict__ vv,
                                               const unsigned short* __restrict__ W1h,
                                               const float* __restrict__ lstm_b,
                                               unsigned short* __restrict__ X1bf) {
    __shared__ __align__(16) unsigned short xs[32 * 256];
    int blk = blockIdx.x;
    int rb = blk >> 3, gb = blk & 7;
    int tid = threadIdx.x;
    for (int it = 0; it < 8; ++it) {
        int idx = it * 256 + tid;
        int row = idx >> 6, f4 = idx & 63;
        float4 v = *reinterpret_cast<const float4*>(vv + (size_t)(rb * 32 + row) * 256 + f4 * 4);
        ushort4 w;
        w.x = f2bf(v.x); w.y = f2bf(v.y); w.z = f2bf(v.z); w.w = f2bf(v.w);
        *reinterpret_cast<ushort4*>(&xs[row * 256 + ((f4 * 4) ^ ((row & 7) << 3))]) = w;
    }
    __syncthreads();
    int wv = tid >> 6, lane = tid & 63, cl = lane & 15, kh = lane >> 4;
    f32x4 acc[2][2];
    for (int n = 0; n < 2; ++n) {
        int nt = gb * 8 + wv * 2 + n;
        float bz = lstm_b[nt * 16 + cl];
        acc[n][0] = (f32x4){bz, bz, bz, bz};
        acc[n][1] = (f32x4){bz, bz, bz, bz};
    }
    #pragma unroll
    for (int kb = 0; kb < 8; ++kb) {
        int k = kb * 32 + kh * 8;
        bf16x8 a0 = *reinterpret_cast<const bf16x8*>(&xs[cl * 256 + (k ^ ((cl & 7) << 3))]);
        bf16x8 a1 = *reinterpret_cast<const bf16x8*>(&xs[(16 + cl) * 256 + (k ^ (((16 + cl) & 7) << 3))]);
        for (int n = 0; n < 2; ++n) {
            int nt = gb * 8 + wv * 2 + n;
            size_t o = ((size_t)(nt * 8 + kb) * 64 + lane) * 8;
            bf16x8 bh = *reinterpret_cast<const bf16x8*>(W1h + o);
            acc[n][0] = __builtin_amdgcn_mfma_f32_16x16x32_bf16(a0, bh, acc[n][0], 0, 0, 0);
            acc[n][1] = __builtin_amdgcn_mfma_f32_16x16x32_bf16(a1, bh, acc[n][1], 0, 0, 0);
        }
    }
    for (int n = 0; n < 2; ++n) {
        int nt = gb * 8 + wv * 2 + n;
        int g = nt * 16 + cl;
        int dX = g & 255, gt = g >> 8;
        for (int mt = 0; mt < 2; ++mt)
            for (int r = 0; r < 4; ++r) {
                int row = rb * 32 + mt * 16 + kh * 4 + r;
                int b = row >> 6, t = row & 63;
                X1bf[((size_t)t * 32 + b) * 1024 + dX * 4 + gt] = f2bf(acc[n][mt][r]);
            }
    }
}

// ---------------------------------------------------------------------------
// lstm_persist: batch-partitioned, i8 weights in VGPR, intra-wg LDS chain.
// 6 wgs x 512 thr: blk 0,1 = A (LSTM1 half); 2,3 = Bi (Wih2*h1); 4,5 = Bh.
// Packing: col n = gate*256 + d; wave w owns d in [w*32,(w+1)*32), all gates.
// flags[0..1023]: A per-wave (t*16 + half*8 + w); [1024..2047]: Bi ditto.
// ---------------------------------------------------------------------------
__global__ void __launch_bounds__(512, 2) lstm_persist(
    const long* __restrict__ Wq, const float* __restrict__ cs,
    const unsigned short* __restrict__ X1bf, const float* __restrict__ hs_b,
    unsigned short* __restrict__ h1bf, unsigned short* __restrict__ h2bf,
    signed char* h1q, unsigned short* p1, int* flags) {
    int role = blockIdx.x;
    int half = role & 1;
    int kind = role >> 1;           // 0 A, 1 Bi, 2 Bh
    int tid = threadIdx.x;
    int w = tid >> 6, lane = tid & 63, c = lane & 15, q = lane >> 4;

    long wt[64];
    #pragma unroll
    for (int t8 = 0; t8 < 8; ++t8)
        #pragma unroll
        for (int kb = 0; kb < 8; ++kb)
            wt[t8 * 8 + kb] = Wq[(size_t)((kind * 512 + w * 64 + t8 * 8 + kb) * 64) + lane];
    float csv[8];
    #pragma unroll
    for (int t8 = 0; t8 < 8; ++t8) {
        int g = t8 >> 1, dt = t8 & 1;
        csv[t8] = cs[kind * 1024 + g * 256 + w * 32 + dt * 16 + c];
    }

    if (kind == 0) {                                    // ---- A: LSTM1 ----
        __shared__ signed char hq[2][16][272];
        float cstate[8] = {0.f, 0.f, 0.f, 0.f, 0.f, 0.f, 0.f, 0.f};
        int B0 = half * 16 + q * 4;
        int dbase = w * 32;
        for (int t = 0; t < 64; ++t) {
            ushort4 xv[8];
            #pragma unroll
            for (int dt = 0; dt < 2; ++dt)
                #pragma unroll
                for (int r = 0; r < 4; ++r) {
                    int B = B0 + r, d = dbase + dt * 16 + c;
                    xv[dt * 4 + r] = *reinterpret_cast<const ushort4*>(
                        X1bf + ((size_t)(t * 32 + B) * 1024 + d * 4));
                }
            i32x4 acc[8];
            #pragma unroll
            for (int i = 0; i < 8; ++i) acc[i] = (i32x4){0, 0, 0, 0};
            if (t > 0) {
                int pb = (t - 1) & 1;
                long a[8];
                #pragma unroll
                for (int kb = 0; kb < 8; ++kb)
                    a[kb] = *reinterpret_cast<const long*>(&hq[pb][c][kb * 32 + q * 8]);
                #pragma unroll
                for (int t8 = 0; t8 < 8; ++t8)
                    #pragma unroll
                    for (int kb = 0; kb < 8; ++kb)
                        acc[t8] = __builtin_amdgcn_mfma_i32_16x16x32_i8(
                            a[kb], wt[t8 * 8 + kb], acc[t8], 0, 0, 0);
            }
            #pragma unroll
            for (int dt = 0; dt < 2; ++dt)
                #pragma unroll
                for (int r = 0; r < 4; ++r) {
                    int idx = dt * 4 + r;
                    ushort4 x = xv[idx];
                    float zi = (float)acc[0 + dt][r] * csv[0 + dt] + bf2f(x.x);
                    float zf = (float)acc[2 + dt][r] * csv[2 + dt] + bf2f(x.y);
                    float zg = (float)acc[4 + dt][r] * csv[4 + dt] + bf2f(x.z);
                    float zo = (float)acc[6 + dt][r] * csv[6 + dt] + bf2f(x.w);
                    float cn = sigm_f(zf) * cstate[idx] + sigm_f(zi) * tanh_f(zg);
                    float hn = sigm_f(zo) * tanh_f(cn);
                    cstate[idx] = cn;
                    int B = B0 + r, d = dbase + dt * 16 + c;
                    h1bf[(size_t)(t * 32 + B) * 256 + d] = f2bf(hn);
                    int hv = __float2int_rn(hn * 127.f);
                    hq[t & 1][q * 4 + r][d] = (signed char)hv;
                    stg_sc_b(h1q + (size_t)(t * 32 + B) * 256 + d, hv);
                }
            asm volatile("s_waitcnt vmcnt(0)" ::: "memory");
            if (lane == 0)
                __hip_atomic_store(flags + t * 16 + half * 8 + w, 1,
                                   __ATOMIC_RELAXED, __HIP_MEMORY_SCOPE_AGENT);
            __syncthreads();
        }
    } else if (kind == 1) {                             // ---- Bi: Wih2*h1 ----
        for (int s = 0; s < 64; ++s) {
            const int* f = flags + s * 16 + half * 8;
            while (1) {
                int v = 1;
                if (lane < 8)
                    v = __hip_atomic_load(f + lane, __ATOMIC_RELAXED, __HIP_MEMORY_SCOPE_AGENT);
                if (__all(v != 0)) break;
                __builtin_amdgcn_s_sleep(1);
            }
            __builtin_amdgcn_sched_barrier(0);
            const signed char* hb = h1q + (size_t)(s * 32 + half * 16) * 256;
            long a[8];
            #pragma unroll
            for (int kb = 0; kb < 8; ++kb)
                a[kb] = ldg_sc8l(hb + c * 256 + kb * 32 + q * 8);
            asm volatile("s_waitcnt vmcnt(0)" ::: "memory");
            __builtin_amdgcn_sched_barrier(0);
            i32x4 acc[8];
            #pragma unroll
            for (int i = 0; i < 8; ++i) acc[i] = (i32x4){0, 0, 0, 0};
            #pragma unroll
            for (int t8 = 0; t8 < 8; ++t8)
                #pragma unroll
                for (int kb = 0; kb < 8; ++kb)
                    acc[t8] = __builtin_amdgcn_mfma_i32_16x16x32_i8(
                        a[kb], wt[t8 * 8 + kb], acc[t8], 0, 0, 0);
            #pragma unroll
            for (int t8 = 0; t8 < 8; ++t8) {
                int g = t8 >> 1, dt = t8 & 1;
                int n = g * 256 + w * 32 + dt * 16 + c;
                u32x2 pv;
                pv.x = (unsigned int)f2bf((float)acc[t8][0] * csv[t8]) |
                       ((unsigned int)f2bf((float)acc[t8][1] * csv[t8]) << 16);
                pv.y = (unsigned int)f2bf((float)acc[t8][2] * csv[t8]) |
                       ((unsigned int)f2bf((float)acc[t8][3] * csv[t8]) << 16);
                stg_sc_u2(p1 + ((size_t)(s * 2 + half) * 1024 + n) * 16 + q * 4, pv);
            }
            asm volatile("s_waitcnt vmcnt(0)" ::: "memory");
            if (lane == 0)
                __hip_atomic_store(flags + 1024 + s * 16 + half * 8 + w, 1,
                                   __ATOMIC_RELAXED, __HIP_MEMORY_SCOPE_AGENT);
        }
    } else {                                            // ---- Bh: LSTM2 ----
        __shared__ signed char hq2[2][16][272];
        float cstate[8] = {0.f, 0.f, 0.f, 0.f, 0.f, 0.f, 0.f, 0.f};
        float bias[8];
        #pragma unroll
        for (int t8 = 0; t8 < 8; ++t8) {
            int g = t8 >> 1, dt = t8 & 1;
            bias[t8] = hs_b[g * 256 + w * 32 + dt * 16 + c];
        }
        int B0 = half * 16 + q * 4;
        int dbase = w * 32;
        for (int s = 0; s < 64; ++s) {
            const int* fp = flags + 1024 + s * 16 + half * 8 + w;
            while (__hip_atomic_load(fp, __ATOMIC_RELAXED, __HIP_MEMORY_SCOPE_AGENT) == 0)
                __builtin_amdgcn_s_sleep(1);
            __builtin_amdgcn_sched_barrier(0);
            u32x2 pv[8];
            #pragma unroll
            for (int t8 = 0; t8 < 8; ++t8) {
                int g = t8 >> 1, dt = t8 & 1;
                int n = g * 256 + w * 32 + dt * 16 + c;
                pv[t8] = ldg_sc_u2(p1 + ((size_t)(s * 2 + half) * 1024 + n) * 16 + q * 4);
            }
            i32x4 acc[8];
            #pragma unroll
            for (int i = 0; i < 8; ++i) acc[i] = (i32x4){0, 0, 0, 0};
            if (s > 0) {
                int pb = (s - 1) & 1;
                long a[8];
                #pragma unroll
                for (int kb = 0; kb < 8; ++kb)
                    a[kb] = *reinterpret_cast<const long*>(&hq2[pb][c][kb * 32 + q * 8]);
                asm volatile("s_waitcnt vmcnt(0)" ::: "memory");
                __builtin_amdgcn_sched_barrier(0);
                #pragma unroll
                for (int t8 = 0; t8 < 8; ++t8)
                    #pragma unroll
                    for (int kb = 0; kb < 8; ++kb)
                        acc[t8] = __builtin_amdgcn_mfma_i32_16x16x32_i8(
                            a[kb], wt[t8 * 8 + kb], acc[t8], 0, 0, 0);
            } else {
                asm volatile("s_waitcnt vmcnt(0)" ::: "memory");
                __builtin_amdgcn_sched_barrier(0);
            }
            #pragma unroll
            for (int dt = 0; dt < 2; ++dt)
                #pragma unroll
                for (int r = 0; r < 4; ++r) {
                    int idx = dt * 4 + r;
                    float p_i = bf2f((unsigned short)((r < 2 ? pv[0 + dt].x : pv[0 + dt].y) >> ((r & 1) * 16)));
                    float p_f = bf2f((unsigned short)((r < 2 ? pv[2 + dt].x : pv[2 + dt].y) >> ((r & 1) * 16)));
                    float p_g = bf2f((unsigned short)((r < 2 ? pv[4 + dt].x : pv[4 + dt].y) >> ((r & 1) * 16)));
                    float p_o = bf2f((unsigned short)((r < 2 ? pv[6 + dt].x : pv[6 + dt].y) >> ((r & 1) * 16)));
                    float zi = (float)acc[0 + dt][r] * csv[0 + dt] + p_i + bias[0 + dt];
                    float zf = (float)acc[2 + dt][r] * csv[2 + dt] + p_f + bias[2 + dt];
                    float zg = (float)acc[4 + dt][r] * csv[4 + dt] + p_g + bias[4 + dt];
                    float zo = (float)acc[6 + dt][r] * csv[6 + dt] + p_o + bias[6 + dt];
                    float cn = sigm_f(zf) * cstate[idx] + sigm_f(zi) * tanh_f(zg);
                    float hn = sigm_f(zo) * tanh_f(cn);
                    cstate[idx] = cn;
                    int B = B0 + r, d = dbase + dt * 16 + c;
                    h2bf[(size_t)(s * 32 + B) * 256 + d] = f2bf(hn);
                    hq2[s & 1][q * 4 + r][d] = (signed char)__float2int_rn(hn * 127.f);
                }
            __syncthreads();
        }
    }
}

// ---------------------------------------------------------------------------
// tail_k: per batch, only v* = lengths[b]-1 matters. Transposed weights.
// ---------------------------------------------------------------------------
__global__ void __launch_bounds__(256) tail_k(
    const int* __restrict__ lengths,
    const unsigned short* __restrict__ h1, const unsigned short* __restrict__ h2,
    const float* __restrict__ whkT, const float* __restrict__ whk_b,
    const float* __restrict__ w1T, const float* __restrict__ w1_b,
    const float* __restrict__ w2_W, const float* __restrict__ w2_b,
    const float* __restrict__ fuseT, const float* __restrict__ fuse_b,
    const float* __restrict__ lab_W, const float* __restrict__ lab_b,
    const float* __restrict__ Wdiff, const float* __restrict__ alpha,
    const float* __restrict__ noise, float* __restrict__ out) {
    __shared__ float ek[256], tv[256], hs[256], whp[256], a1s[64];
    __shared__ float noisy_s[256], fin[512], fused_s[256], attn_s[2];
    int b = blockIdx.x, tid = threadIdx.x;
    int vstar = lengths[b] - 1;
    {
        ek[tid] = bf2f(h1[(size_t)b * 256 + tid]);
        tv[tid] = bf2f(h1[((size_t)vstar * 32 + b) * 256 + tid]);
        if (vstar > 0)
            hs[tid] = bf2f(h2[((size_t)(vstar - 1) * 32 + b) * 256 + tid]);
    }
    __syncthreads();

    float aligned;
    if (vstar > 0) {
        float s0 = 0.f, s1 = 0.f, s2 = 0.f, s3 = 0.f;
        for (int k = 0; k < 256; k += 4) {
            s0 += whkT[(k + 0) * 256 + tid] * hs[k + 0];
            s1 += whkT[(k + 1) * 256 + tid] * hs[k + 1];
            s2 += whkT[(k + 2) * 256 + tid] * hs[k + 2];
            s3 += whkT[(k + 3) * 256 + tid] * hs[k + 3];
        }
        whp[tid] = whk_b[tid] + s0 + s1 + s2 + s3;
        __syncthreads();
        if (tid < 64) {
            float a0 = 0.f, a1 = 0.f, a2 = 0.f, a3 = 0.f;
            for (int k = 0; k < 256; k += 4) {
                a0 += w1T[(k + 0) * 64 + tid] * ek[k + 0];
                a1 += w1T[(k + 1) * 64 + tid] * ek[k + 1];
                a2 += w1T[(k + 2) * 64 + tid] * ek[k + 2];
                a3 += w1T[(k + 3) * 64 + tid] * ek[k + 3];
            }
            for (int k = 0; k < 256; k += 4) {
                a0 += w1T[(256 + k + 0) * 64 + tid] * whp[k + 0];
                a1 += w1T[(256 + k + 1) * 64 + tid] * whp[k + 1];
                a2 += w1T[(256 + k + 2) * 64 + tid] * whp[k + 2];
                a3 += w1T[(256 + k + 3) * 64 + tid] * whp[k + 3];
            }
            a1s[tid] = tanhf(w1_b[tid] + a0 + a1 + a2 + a3);
        }
        __syncthreads();
        if (tid < 2) {
            float a3 = w2_b[tid];
            const float* wr2 = w2_W + tid * 64;
            for (int k = 0; k < 64; ++k) a3 += wr2[k] * a1s[k];
            attn_s[tid] = a3;
        }
        __syncthreads();
        float m = fmaxf(attn_s[0], attn_s[1]);
        float e0 = __expf(attn_s[0] - m), e1 = __expf(attn_s[1] - m);
        float inv = 1.f / (e0 + e1);
        aligned = ek[tid] * (e0 * inv) + whp[tid] * (e1 * inv);
    } else {
        aligned = ek[tid];
    }

    float al = alpha[b];
    float sa = sqrtf(al), sb = sqrtf(1.f - al);
    float nz = noise[((size_t)b * 64 + vstar) * 256 + tid];
    noisy_s[tid] = aligned * sa + nz * sb;
    __syncthreads();
    {
        float p0 = 0.f, p1v = 0.f, p2 = 0.f, p3 = 0.f;
        for (int k = 0; k < 256; k += 4) {
            p0 += noisy_s[k + 0] * Wdiff[(size_t)(k + 0) * 256 + tid];
            p1v += noisy_s[k + 1] * Wdiff[(size_t)(k + 1) * 256 + tid];
            p2 += noisy_s[k + 2] * Wdiff[(size_t)(k + 2) * 256 + tid];
            p3 += noisy_s[k + 3] * Wdiff[(size_t)(k + 3) * 256 + tid];
        }
        float gen = aligned + nz - (p0 + p1v + p2 + p3);
        fin[tid] = tv[tid];
        fin[256 + tid] = gen;
    }
    __syncthreads();
    {
        float f0 = 0.f, f1 = 0.f, f2 = 0.f, f3 = 0.f;
        for (int k = 0; k < 512; k += 4) {
            f0 += fuseT[(k + 0) * 256 + tid] * fin[k + 0];
            f1 += fuseT[(k + 1) * 256 + tid] * fin[k + 1];
            f2 += fuseT[(k + 2) * 256 + tid] * fin[k + 2];
            f3 += fuseT[(k + 3) * 256 + tid] * fin[k + 3];
        }
        fused_s[tid] = fuse_b[tid] + f0 + f1 + f2 + f3;
    }
    __syncthreads();
    if (tid < 2) {
        float o = lab_b[tid];
        const float* lw = lab_W + tid * 256;
        for (int k = 0; k < 256; ++k) o += lw[k] * fused_s[k];
        out[b * 2 + tid] = o;
    }
}

// ---------------------------------------------------------------------------
extern "C" void kernel_launch(void* const* d_in, const int* in_sizes, int n_in,
                              void* d_out, int out_size, void* d_ws, size_t ws_size,
                              hipStream_t stream) {
    const int*   seqs    = (const int*)  d_in[0];
    const int*   lengths = (const int*)  d_in[2];
    const float* tstep   = (const float*)d_in[3];
    const float* cmask   = (const float*)d_in[4];
    const float* emb     = (const float*)d_in[5];
    const float* WQ1     = (const float*)d_in[6];
    const float* WK1     = (const float*)d_in[7];
    const float* decay   = (const float*)d_in[8];
    const float* initial = (const float*)d_in[9];
    const float* Wih1    = (const float*)d_in[10];
    const float* Whh1    = (const float*)d_in[11];
    const float* lstm_b  = (const float*)d_in[12];
    const float* Wih2    = (const float*)d_in[13];
    const float* Whh2    = (const float*)d_in[14];
    const float* hs_b    = (const float*)d_in[15];
    const float* whk_W   = (const float*)d_in[16];
    const float* whk_b   = (const float*)d_in[17];
    const float* w1_W    = (const float*)d_in[18];
    const float* w1_b    = (const float*)d_in[19];
    const float* w2_W    = (const float*)d_in[20];
    const float* w2_b    = (const float*)d_in[21];
    const float* fuse_W  = (const float*)d_in[22];
    const float* fuse_b  = (const float*)d_in[23];
    const float* lab_W   = (const float*)d_in[24];
    const float* lab_b   = (const float*)d_in[25];
    const float* betas   = (const float*)d_in[26];
    const float* Wdiff   = (const float*)d_in[27];
    const int*   dift    = (const int*)  d_in[28];
    const float* noise   = (const float*)d_in[29];
    float* out = (float*)d_out;

    float* ws = (float*)d_ws;
    size_t off = 0;
    auto alloc = [&](size_t nfloats) { size_t r = off; off += (nfloats + 63) & ~(size_t)63; return r; };
    unsigned short* M_pk  = (unsigned short*)(ws + alloc(32768));
    float*          alpha = ws + alloc(64);
    float*          cs    = ws + alloc(3072);
    int*            flags = (int*)(ws + alloc(2048));
    float*          vv    = ws + alloc(524288);          // dead after x1_mfma
    unsigned short* X1bf  = (unsigned short*)(ws + alloc(1048576));
    unsigned short* h1bf  = (unsigned short*)(ws + alloc(262144));
    unsigned short* h2bf  = (unsigned short*)(ws + alloc(262144));
    unsigned short* p1    = (unsigned short*)(ws + alloc(1048576));
    long*           Wq    = (long*)(ws + alloc(196608));
    unsigned short* W1h   = (unsigned short*)(ws + alloc(131072));
    float*          whkT  = ws + alloc(65536);
    float*          fuseT = ws + alloc(131072);
    float*          w1T   = ws + alloc(32768);
    signed char*    h1q   = (signed char*)vv;            // alias: lstm-phase only

    pack_all<<<802, 256, 0, stream>>>(Whh1, Wih2, Whh2, Wih1, WQ1, WK1, betas, dift,
                                      whk_W, fuse_W, w1_W,
                                      Wq, cs, W1h, M_pk, alpha, flags,
                                      whkT, fuseT, w1T);
    attn_bags<<<2048, 256, 0, stream>>>(seqs, tstep, cmask, emb, decay, initial, M_pk, vv);
    x1_mfma<<<512, 256, 0, stream>>>(vv, W1h, lstm_b, X1bf);
    lstm_persist<<<6, 512, 0, stream>>>(Wq, cs, X1bf, hs_b, h1bf, h2bf, h1q, p1, flags);
    tail_k<<<32, 256, 0, stream>>>(lengths, h1bf, h2bf, whkT, whk_b,
                                   w1T, w1_b, w2_W, w2_b, fuseT, fuse_b,
                                   lab_W, lab_b, Wdiff, alpha, noise, out);
}